// Round 11
// baseline (289.644 us; speedup 1.0000x reference)
//
#include <hip/hip_runtime.h>
#include <hip/hip_bf16.h>

// Problem constants (fixed by the reference's setup_inputs)
#define N_NODES 10000
#define N_EDGES 4000
#define IN_CH   128
#define HOC     128   // HEADS*OUT_CH (internal width of W1/W2)
#define OUT_CH  64    // folded gather width = OUT_CH
#define CHUNK   16384 // entries per counting-sort block (scale-2)
#define SEG     256   // entries per gather half-wave segment (scale-2)

#define G_GEMM  625   // N_NODES/16
#define G_ZERO  512
#define G_NPTR  40    // ceil(10001/256)

__device__ __forceinline__ float bf2f(unsigned short u) {
    union { unsigned int i; float f; } v;
    v.i = ((unsigned int)u) << 16;
    return v.f;
}
__device__ __forceinline__ unsigned short f2bfu(float f) {
    union { __hip_bfloat16 h; unsigned short u; } v;
    v.h = __float2bfloat16(f);
    return v.u;
}

// load 8 consecutive float values from either fp32 or packed-bf16 storage.
__device__ __forceinline__ void load8(const void* base, size_t eoff, int isf32,
                                      float o[8]) {
    if (isf32) {
        const float4* q = (const float4*)((const float*)base + eoff);
        float4 a = q[0], b = q[1];
        o[0]=a.x; o[1]=a.y; o[2]=a.z; o[3]=a.w;
        o[4]=b.x; o[5]=b.y; o[6]=b.z; o[7]=b.w;
    } else {
        uint4 v = *(const uint4*)((const unsigned short*)base + eoff);
        const unsigned short* pv = (const unsigned short*)&v;
#pragma unroll
        for (int q = 0; q < 8; q++) o[q] = bf2f(pv[q]);
    }
}

__device__ __forceinline__ float loadS(const void* base, int i, int isf32) {
    return isf32 ? ((const float*)base)[i] : bf2f(((const unsigned short*)base)[i]);
}

// Per-wave inline dtype probe of x's first 512 bytes. 1 = fp32, 0 = bf16.
__device__ __forceinline__ int probe_isf32(const unsigned int* __restrict__ x) {
    const int lane = threadIdx.x & 63;
    unsigned int w0 = x[lane * 2], w1 = x[lane * 2 + 1];
    int h = 0, z = 0;
    {
        unsigned int lo = w0 & 0xFFFFu;
        if (lo == 0u) z++; else if (((lo >> 7) & 0xFF) >= 0x90u) h++;
        lo = w1 & 0xFFFFu;
        if (lo == 0u) z++; else if (((lo >> 7) & 0xFF) >= 0x90u) h++;
    }
    unsigned long long bh = __ballot(h > 0);
    unsigned long long bz = __ballot(z == 2);
    return (__popcll(bh) > 8 || __popcll(bz) > 50) ? 1 : 0;
}

// ---------------------------------------------------------------------------
// Dispatch 0: W_eff_s = 0.5*Wout@W_s (64x128), beff_s = 0.5*Wout@b_s, and
// zero the 18000-int count block. Blocks 0/1 = scales; block 2 = zero.
__global__ __launch_bounds__(256) void weff_zero(
    const void* __restrict__ Wout,
    const void* __restrict__ W1, const void* __restrict__ b1,
    const void* __restrict__ W2, const void* __restrict__ b2,
    float* __restrict__ weff1, float* __restrict__ beff1,
    float* __restrict__ weff2, float* __restrict__ beff2,
    int* __restrict__ cntz, const unsigned int* __restrict__ xprobe)
{
    if (blockIdx.x == 2) {
        for (int t = threadIdx.x; t < 18000; t += 256) cntz[t] = 0;
        return;
    }
    const int s = blockIdx.x;
    const void* Ws = s ? W2 : W1;
    const void* bs = s ? b2 : b1;
    float* outW = s ? weff2 : weff1;
    float* outb = s ? beff2 : beff1;
    const int isf32 = probe_isf32(xprobe);

    __shared__ float wsh[64][IN_CH];     // 32 KB: 64 rows of W_s at a time
    const int o  = threadIdx.x >> 2;       // 0..63 output row
    const int i0 = (threadIdx.x & 3) * 32; // column chunk
    float acc[32];
#pragma unroll
    for (int k = 0; k < 32; k++) acc[k] = 0.f;

    for (int pass = 0; pass < 2; pass++) {
        for (int r = 0; r < 4; r++) {
            int idx = r * 2048 + threadIdx.x * 8;
            float v[8];
            load8(Ws, (size_t)pass * 8192 + idx, isf32, v);
            float* d = &wsh[0][0] + idx;
#pragma unroll
            for (int q = 0; q < 8; q++) d[q] = v[q];
        }
        __syncthreads();
        for (int h = 0; h < 64; h++) {
            float wo = loadS(Wout, o * 128 + pass * 64 + h, isf32);
            const float* wr = &wsh[h][i0];
#pragma unroll
            for (int k = 0; k < 32; k++) acc[k] += wo * wr[k];
        }
        __syncthreads();
    }
#pragma unroll
    for (int k = 0; k < 32; k++) outW[o * 128 + i0 + k] = 0.5f * acc[k];

    if (threadIdx.x < 64) {
        float a = 0.f;
        for (int h = 0; h < 128; h++)
            a += loadS(Wout, threadIdx.x * 128 + h, isf32) * loadS(bs, h, isf32);
        outb[threadIdx.x] = 0.5f * a;
    }
}

// ---------------------------------------------------------------------------
// MEGA-PREP: block-range fused, all roles mutually independent.
//  [0, nblk)        hist2 -> bh + cnt2 atomics (cnt pre-zeroed by weff_zero)
//  [nblk, nblk+8)   hist1 -> cnt1e/cnt1n atomics
//  [.., +G_GEMM)    gemm: xtP_s = x@W_eff_s^T + beff_s (bf16, 64 cols)
//  [.., +G_ZERO)    zero: o64 + fill1e + fill1n + esum2f (grid-stride)
//  [.., +G_NPTR)    nptr: lower_bound(idx2, n)
__global__ __launch_bounds__(256) void prep(
    const void* __restrict__ x,
    const float* __restrict__ weff1, const float* __restrict__ beff1,
    const float* __restrict__ weff2, const float* __restrict__ beff2,
    unsigned short* __restrict__ xtP1b, unsigned short* __restrict__ xtP2b,
    const int* __restrict__ idx1, int nnz1,
    const int* __restrict__ idx2, int nnz2,
    int* __restrict__ nptr, float4* __restrict__ zerobase, int zeroN4,
    int* __restrict__ bh, int* __restrict__ cnt2,
    int* __restrict__ cnt1e, int* __restrict__ cnt1n, int nblk)
{
    __shared__ __align__(16) char smem[40000];
    int b = blockIdx.x;

    if (b < nblk) {                     // ---- hist2 ----
        int* h = (int*)smem;
        for (int t = threadIdx.x; t < N_EDGES; t += 256) h[t] = 0;
        __syncthreads();
        const int lo = b * CHUNK;
        const int hi = min(nnz2, lo + CHUNK);
        for (int i = lo + threadIdx.x; i < hi; i += 256)
            atomicAdd(&h[idx2[nnz2 + i]], 1);
        __syncthreads();
        int* dst = bh + (size_t)b * N_EDGES;
        for (int t = threadIdx.x; t < N_EDGES; t += 256) {
            int v = h[t];
            dst[t] = v;
            if (v) atomicAdd(&cnt2[t], v);
        }
        return;
    }
    b -= nblk;

    if (b < 8) {                        // ---- hist1 ----
        const int isEdge = b < 4;
        const int bid = isEdge ? b : (b - 4);
        const int nb = isEdge ? N_EDGES : N_NODES;
        const int* src = isEdge ? (idx1 + nnz1) : idx1;
        int* dst = isEdge ? cnt1e : cnt1n;
        int* h = (int*)smem;
        for (int t = threadIdx.x; t < nb; t += 256) h[t] = 0;
        __syncthreads();
        for (int i = bid * 256 + threadIdx.x; i < nnz1; i += 4 * 256)
            atomicAdd(&h[src[i]], 1);
        __syncthreads();
        for (int t = threadIdx.x; t < nb; t += 256) {
            int v = h[t];
            if (v) atomicAdd(&dst[t], v);
        }
        return;
    }
    b -= 8;

    if (b < G_GEMM) {                   // ---- gemm (64-col folded) ----
        const int isf32 = probe_isf32((const unsigned int*)x);
        float (*xs)[IN_CH] = (float (*)[IN_CH])smem;
        const int n0 = b * 16;
        {
            float v[8];
            load8(x, (size_t)n0 * IN_CH + (size_t)threadIdx.x * 8, isf32, v);
            float* dst = &xs[0][0] + threadIdx.x * 8;
#pragma unroll
            for (int q = 0; q < 8; q++) dst[q] = v[q];
        }
        __syncthreads();

        const int g   = threadIdx.x >> 7;      // node half: 0 -> 0..7, 1 -> 8..15
        const int sel = (threadIdx.x >> 6) & 1;
        const int j   = threadIdx.x & 63;      // output column (of 64)
        const float* WE = sel ? weff2 : weff1;
        const float* BE = sel ? beff2 : beff1;
        unsigned short* xtP = sel ? xtP2b : xtP1b;

        float acc[8];
#pragma unroll
        for (int m = 0; m < 8; m++) acc[m] = 0.f;

        const float4* Wr = (const float4*)(WE + (size_t)j * 128);
        for (int kk = 0; kk < 16; kk++) {
            float4 a = Wr[kk * 2], c = Wr[kk * 2 + 1];
            float w[8] = {a.x, a.y, a.z, a.w, c.x, c.y, c.z, c.w};
#pragma unroll
            for (int m = 0; m < 8; m++) {
                const float* xr = &xs[g * 8 + m][kk * 8];
                acc[m] += xr[0]*w[0] + xr[1]*w[1] + xr[2]*w[2] + xr[3]*w[3]
                        + xr[4]*w[4] + xr[5]*w[5] + xr[6]*w[6] + xr[7]*w[7];
            }
        }
        const float bias = BE[j];
#pragma unroll
        for (int m = 0; m < 8; m++)
            xtP[(size_t)(n0 + g * 8 + m) * 64 + j] = f2bfu(acc[m] + bias);
        return;
    }
    b -= G_GEMM;

    if (b < G_ZERO) {                   // ---- zero ----
        for (int t = b * 256 + threadIdx.x; t < zeroN4; t += G_ZERO * 256)
            zerobase[t] = make_float4(0.f, 0.f, 0.f, 0.f);
        return;
    }
    b -= G_ZERO;

    {                                   // ---- nptr ----
        int n = b * 256 + threadIdx.x;
        if (n > N_NODES) return;
        int lo = 0, hi = nnz2;
        while (lo < hi) { int mid = (lo + hi) >> 1; if (idx2[mid] < n) lo = mid + 1; else hi = mid; }
        nptr[n] = lo;
    }
}

// ---------------------------------------------------------------------------
// 3-block exclusive scans over the count arrays.
__global__ __launch_bounds__(256) void scans3(
    const int* __restrict__ cnt2, int* __restrict__ ptr2,
    const int* __restrict__ cnt1e, int* __restrict__ ptr1e,
    const int* __restrict__ cnt1n, int* __restrict__ ptr1n)
{
    const int* cnt; int* ptr; int nb;
    if (blockIdx.x == 0)      { cnt = cnt2;  ptr = ptr2;  nb = N_EDGES; }
    else if (blockIdx.x == 1) { cnt = cnt1e; ptr = ptr1e; nb = N_EDGES; }
    else                      { cnt = cnt1n; ptr = ptr1n; nb = N_NODES; }
    __shared__ int part[256];
    const int t = threadIdx.x;
    const int K = (nb + 255) >> 8;
    const int base = t * K;
    int s = 0;
    for (int q = 0; q < K; q++) {
        int i = base + q;
        s += (i < nb) ? cnt[i] : 0;
    }
    part[t] = s;
    __syncthreads();
    for (int d = 1; d < 256; d <<= 1) {
        int v = (t >= d) ? part[t - d] : 0;
        __syncthreads();
        part[t] += v;
        __syncthreads();
    }
    int run = part[t] - s;
    for (int q = 0; q < K; q++) {
        int i = base + q;
        if (i < nb) { ptr[i] = run; run += cnt[i]; }
    }
    if (t == 255) ptr[nb] = part[255];
}

// ---------------------------------------------------------------------------
// Fused: scan_blocks (bh counts -> per-block bases) + fill_both (scale-1 lists)
__global__ __launch_bounds__(256) void sb_fb(
    const int* __restrict__ ptr2, int* __restrict__ bh, int nblk,
    const int* __restrict__ idx1, int nnz1,
    const int* __restrict__ ptr1e, int* __restrict__ fill1e,
    unsigned short* __restrict__ nodelist1,
    const int* __restrict__ ptr1n, int* __restrict__ fill1n,
    unsigned short* __restrict__ edgelist1)
{
    int b = blockIdx.x;
    if (b < 16) {
        int e = b * 256 + threadIdx.x;
        if (e >= N_EDGES) return;
        int run = ptr2[e];
        for (int k = 0; k < nblk; k++) {
            int i = k * N_EDGES + e;
            int t = bh[i];
            bh[i] = run;
            run += t;
        }
        return;
    }
    b -= 16;
    int i = b * 256 + threadIdx.x;
    if (i >= nnz1) return;
    int n = idx1[i];
    int e = idx1[nnz1 + i];
    int se = atomicAdd(&fill1e[e], 1);
    nodelist1[ptr1e[e] + se] = (unsigned short)n;
    int sn = atomicAdd(&fill1n[n], 1);
    edgelist1[ptr1n[n] + sn] = (unsigned short)e;
}

// ---------------------------------------------------------------------------
// scale-2 placement with LDS slot counters
__global__ __launch_bounds__(256) void place_entries(
    const int* __restrict__ idx, int nnz, const int* __restrict__ bh,
    unsigned short* __restrict__ nodelist)
{
    __shared__ int lh[N_EDGES];
    for (int t = threadIdx.x; t < N_EDGES; t += 256) lh[t] = 0;
    __syncthreads();
    const int b = blockIdx.x;
    const int lo = b * CHUNK;
    const int hi = min(nnz, lo + CHUNK);
    const int* bhb = bh + (size_t)b * N_EDGES;
    for (int i = lo + threadIdx.x; i < hi; i += 256) {
        int n = idx[i];
        int e = idx[nnz + i];
        int s = atomicAdd(&lh[e], 1);
        nodelist[bhb[e] + s] = (unsigned short)n;
    }
}

// ---------------------------------------------------------------------------
// Fused edge gathers, 64 channels, HALF-WAVE (32-lane) groups.
//  [0, segB): s2 segment-parallel sums into esum2f (8-wide ILP + flush)
//  [segB, segB+500): s1 half-wave-per-edge mean (fused div+pack)
__global__ __launch_bounds__(256) void edge_gather(
    const unsigned short* __restrict__ nodelist2, const int* __restrict__ ptr2,
    int nnz2, const unsigned int* __restrict__ xtP2u, float* __restrict__ esum2f,
    int segB,
    const unsigned short* __restrict__ nodelist1, const int* __restrict__ ptr1e,
    const unsigned int* __restrict__ xtP1u, unsigned int* __restrict__ emean1b)
{
    const int lane = threadIdx.x & 31;
    int b = blockIdx.x;
    if (b < segB) {
        const int hw = (b * 256 + threadIdx.x) >> 5;
        const int s = hw * SEG;
        if (s >= nnz2) return;
        const int e_end = min(nnz2, s + SEG);
        int lo = 0, hi = N_EDGES;
        while (lo < hi) { int mid = (lo + hi) >> 1; if (ptr2[mid] <= s) lo = mid + 1; else hi = mid; }
        int g = lo - 1;
        int next = ptr2[g + 1];
        float accx = 0.f, accy = 0.f;
        for (int i = s; i < e_end; i += 32) {
            const int m = min(32, e_end - i);
            int vl = (i + lane < e_end) ? (int)nodelist2[i + lane] : 0;
            int j = 0;
            while (j < m) {
                while (i + j >= next) {
                    unsafeAtomicAdd(esum2f + (size_t)g * 64 + 2 * lane,     accx);
                    unsafeAtomicAdd(esum2f + (size_t)g * 64 + 2 * lane + 1, accy);
                    accx = accy = 0.f;
                    g++;
                    next = ptr2[g + 1];
                }
                int run = min(m - j, next - (i + j));
                int t = 0;
                for (; t + 7 < run; t += 8) {
                    int nn[8]; unsigned int uu[8];
#pragma unroll
                    for (int q = 0; q < 8; q++) nn[q] = __shfl(vl, j + t + q, 32);
#pragma unroll
                    for (int q = 0; q < 8; q++) uu[q] = xtP2u[nn[q] * 32 + lane];
#pragma unroll
                    for (int q = 0; q < 8; q++) {
                        accx += bf2f((unsigned short)(uu[q] & 0xFFFFu));
                        accy += bf2f((unsigned short)(uu[q] >> 16));
                    }
                }
                for (; t < run; t++) {
                    int n = __shfl(vl, j + t, 32);
                    unsigned int u = xtP2u[n * 32 + lane];
                    accx += bf2f((unsigned short)(u & 0xFFFFu));
                    accy += bf2f((unsigned short)(u >> 16));
                }
                j += run;
            }
        }
        unsafeAtomicAdd(esum2f + (size_t)g * 64 + 2 * lane,     accx);
        unsafeAtomicAdd(esum2f + (size_t)g * 64 + 2 * lane + 1, accy);
        return;
    }
    b -= segB;
    {   // scale-1 half-wave-per-edge mean
        const int e = b * 8 + (threadIdx.x >> 5);
        const int lo = ptr1e[e], hi = ptr1e[e + 1];
        float accx = 0.f, accy = 0.f;
        for (int base = lo; base < hi; base += 32) {
            const int m = min(32, hi - base);
            int vl = (base + lane < hi) ? (int)nodelist1[base + lane] : 0;
            int t = 0;
            for (; t + 7 < m; t += 8) {
                int nn[8]; unsigned int uu[8];
#pragma unroll
                for (int q = 0; q < 8; q++) nn[q] = __shfl(vl, t + q, 32);
#pragma unroll
                for (int q = 0; q < 8; q++) uu[q] = xtP1u[nn[q] * 32 + lane];
#pragma unroll
                for (int q = 0; q < 8; q++) {
                    accx += bf2f((unsigned short)(uu[q] & 0xFFFFu));
                    accy += bf2f((unsigned short)(uu[q] >> 16));
                }
            }
            for (; t < m; t++) {
                int n = __shfl(vl, t, 32);
                unsigned int u = xtP1u[n * 32 + lane];
                accx += bf2f((unsigned short)(u & 0xFFFFu));
                accy += bf2f((unsigned short)(u >> 16));
            }
        }
        const float inv = 1.f / fmaxf((float)(hi - lo), 1.f);
        emean1b[e * 32 + lane] =
            ((unsigned int)f2bfu(accy * inv) << 16) | f2bfu(accx * inv);
    }
}

// ---------------------------------------------------------------------------
// s2 mean + pack to bf16x2 (counts from ptr2 diffs); 4000x32 uints
__global__ __launch_bounds__(256) void pack2(
    const float* __restrict__ esum2f, const int* __restrict__ ptr2,
    unsigned int* __restrict__ emean2b)
{
    int t = blockIdx.x * 256 + threadIdx.x;   // t < N_EDGES*32
    int e = t >> 5;
    float inv = 1.f / fmaxf((float)(ptr2[e + 1] - ptr2[e]), 1.f);
    float2 v = *(const float2*)(esum2f + (size_t)t * 2);
    emean2b[t] = ((unsigned int)f2bfu(v.y * inv) << 16) | f2bfu(v.x * inv);
}

// ---------------------------------------------------------------------------
// Fused node gathers into zeroed o64 (both scales atomic):
//  [0, segB): s2 segment-parallel; [segB, +1250): s1 half-wave-per-node.
__global__ __launch_bounds__(256) void node_gather(
    const int* __restrict__ vals2, const int* __restrict__ nptr, int nnz2,
    const unsigned int* __restrict__ emean2b, float* __restrict__ o64, int segB,
    const unsigned short* __restrict__ edgelist1, const int* __restrict__ ptr1n,
    const unsigned int* __restrict__ emean1b)
{
    const int lane = threadIdx.x & 31;
    int b = blockIdx.x;
    if (b < segB) {
        const int hw = (b * 256 + threadIdx.x) >> 5;
        const int s = hw * SEG;
        if (s >= nnz2) return;
        const int e_end = min(nnz2, s + SEG);
        int lo = 0, hi = N_NODES;
        while (lo < hi) { int mid = (lo + hi) >> 1; if (nptr[mid] <= s) lo = mid + 1; else hi = mid; }
        int g = lo - 1;
        int next = nptr[g + 1];
        float accx = 0.f, accy = 0.f;
        for (int i = s; i < e_end; i += 32) {
            const int m = min(32, e_end - i);
            int vl = (i + lane < e_end) ? vals2[i + lane] : 0;
            int j = 0;
            while (j < m) {
                while (i + j >= next) {
                    unsafeAtomicAdd(o64 + (size_t)g * 64 + 2 * lane,     accx);
                    unsafeAtomicAdd(o64 + (size_t)g * 64 + 2 * lane + 1, accy);
                    accx = accy = 0.f;
                    g++;
                    next = nptr[g + 1];
                }
                int run = min(m - j, next - (i + j));
                int t = 0;
                for (; t + 7 < run; t += 8) {
                    int ee[8]; unsigned int uu[8];
#pragma unroll
                    for (int q = 0; q < 8; q++) ee[q] = __shfl(vl, j + t + q, 32);
#pragma unroll
                    for (int q = 0; q < 8; q++) uu[q] = emean2b[ee[q] * 32 + lane];
#pragma unroll
                    for (int q = 0; q < 8; q++) {
                        accx += bf2f((unsigned short)(uu[q] & 0xFFFFu));
                        accy += bf2f((unsigned short)(uu[q] >> 16));
                    }
                }
                for (; t < run; t++) {
                    int e = __shfl(vl, j + t, 32);
                    unsigned int u = emean2b[e * 32 + lane];
                    accx += bf2f((unsigned short)(u & 0xFFFFu));
                    accy += bf2f((unsigned short)(u >> 16));
                }
                j += run;
            }
        }
        unsafeAtomicAdd(o64 + (size_t)g * 64 + 2 * lane,     accx);
        unsafeAtomicAdd(o64 + (size_t)g * 64 + 2 * lane + 1, accy);
        return;
    }
    b -= segB;
    {   // scale-1 half-wave-per-node
        const int n = b * 8 + (threadIdx.x >> 5);
        const int lo = ptr1n[n], hi = ptr1n[n + 1];
        if (lo == hi) return;
        float accx = 0.f, accy = 0.f;
        for (int base = lo; base < hi; base += 32) {
            const int m = min(32, hi - base);
            int vl = (base + lane < hi) ? (int)edgelist1[base + lane] : 0;
            int t = 0;
            for (; t + 7 < m; t += 8) {
                int ee[8]; unsigned int uu[8];
#pragma unroll
                for (int q = 0; q < 8; q++) ee[q] = __shfl(vl, t + q, 32);
#pragma unroll
                for (int q = 0; q < 8; q++) uu[q] = emean1b[ee[q] * 32 + lane];
#pragma unroll
                for (int q = 0; q < 8; q++) {
                    accx += bf2f((unsigned short)(uu[q] & 0xFFFFu));
                    accy += bf2f((unsigned short)(uu[q] >> 16));
                }
            }
            for (; t < m; t++) {
                int e = __shfl(vl, t, 32);
                unsigned int u = emean1b[e * 32 + lane];
                accx += bf2f((unsigned short)(u & 0xFFFFu));
                accy += bf2f((unsigned short)(u >> 16));
            }
        }
        unsafeAtomicAdd(o64 + (size_t)n * 64 + 2 * lane,     accx);
        unsafeAtomicAdd(o64 + (size_t)n * 64 + 2 * lane + 1, accy);
    }
}

// ---------------------------------------------------------------------------
// final: out[n][c] = o64[n][c] + bout[c]   (projection already folded)
__global__ __launch_bounds__(256) void final_out(
    const float* __restrict__ o64, const void* __restrict__ bout,
    void* __restrict__ out, const unsigned int* __restrict__ xprobe)
{
    const int isf32 = probe_isf32(xprobe);
    int t = blockIdx.x * 256 + threadIdx.x;   // t < N_NODES*32
    int c = t & 31;
    float2 v = *(const float2*)(o64 + (size_t)t * 2);
    float r0 = v.x + loadS(bout, 2 * c, isf32);
    float r1 = v.y + loadS(bout, 2 * c + 1, isf32);
    if (isf32) ((float2*)out)[t] = make_float2(r0, r1);
    else ((unsigned int*)out)[t] = ((unsigned int)f2bfu(r1) << 16) | f2bfu(r0);
}

// ---------------------------------------------------------------------------
extern "C" void kernel_launch(void* const* d_in, const int* in_sizes, int n_in,
                              void* d_out, int out_size, void* d_ws, size_t ws_size,
                              hipStream_t stream)
{
    const void* x  = d_in[0];
    const int* idx1 = (const int*)d_in[1];
    const int* idx2 = (const int*)d_in[2];
    const void* W1 = d_in[3];
    const void* b1 = d_in[4];
    const void* W2 = d_in[5];
    const void* b2 = d_in[6];
    const void* Wo = d_in[7];
    const void* bo = d_in[8];

    const int nnz1 = in_sizes[1] / 2;
    const int nnz2 = in_sizes[2] / 2;
    const int nblk = (nnz2 + CHUNK - 1) / CHUNK;

    // ---- workspace layout (units of 4 bytes) ----
    float* ws = (float*)d_ws;
    unsigned short* xtP1b = (unsigned short*)ws;              // [0 .. 320,000)
    unsigned int*   xtP1u = (unsigned int*)xtP1b;
    unsigned short* xtP2b = (unsigned short*)(ws + 320000);   // [.. 640,000)
    unsigned int*   xtP2u = (unsigned int*)xtP2b;
    float* o64    = ws + 640000;            // 640,000   --- zero span start
    int*   fill1e = (int*)(ws + 1280000);   //   4,000
    int*   fill1n = (int*)(ws + 1284000);   //  10,000
    float* esum2f = ws + 1294000;           // 256,000   --- zero span end
    // zero span: [640,000 .. 1,550,000) = 910,000 floats = 227,500 f4
    int* cnt2  = (int*)(ws + 1550000);      //  4,000  --- int-zero span (18,000)
    int* cnt1e = (int*)(ws + 1554000);      //  4,000
    int* cnt1n = (int*)(ws + 1558000);      // 10,000
    int* ptr2  = (int*)(ws + 1568000);      //  4,001
    int* ptr1e = (int*)(ws + 1572004);      //  4,001
    int* ptr1n = (int*)(ws + 1576008);      // 10,001
    int* nptr  = (int*)(ws + 1586012);      // 10,001
    float* weff1 = ws + 1596016;            //  8,192
    float* weff2 = ws + 1604208;            //  8,192
    float* beff1 = ws + 1612400;            //     64
    float* beff2 = ws + 1612464;            //     64
    unsigned int* emean2b = (unsigned int*)(ws + 1612528);   // 128,000
    unsigned int* emean1b = (unsigned int*)(ws + 1740528);   // 128,000
    unsigned short* nodelist2 = (unsigned short*)(ws + 1868528);
    const size_t nl2u = ((size_t)nnz2 + 1) / 2;
    unsigned short* nodelist1 = (unsigned short*)(ws + 1868528 + nl2u);
    const size_t nl1u = ((size_t)nnz1 + 1) / 2;
    unsigned short* edgelist1 = (unsigned short*)(ws + 1868528 + nl2u + nl1u);
    const size_t bh_off = (1868528 + nl2u + 2 * nl1u + 7) & ~(size_t)7;
    int* bh = (int*)(ws + bh_off);

    const int segB = ((nnz2 + SEG - 1) / SEG + 7) / 8;

    // 0) W_eff precompute + zero count arrays
    weff_zero<<<3, 256, 0, stream>>>(Wo, W1, b1, W2, b2,
                                     weff1, beff1, weff2, beff2,
                                     cnt2, (const unsigned int*)x);

    // 1) mega-prep: hist2 | hist1 | gemm(64) | zero | nptr
    prep<<<nblk + 8 + G_GEMM + G_ZERO + G_NPTR, 256, 0, stream>>>(
        x, weff1, beff1, weff2, beff2, xtP1b, xtP2b,
        idx1, nnz1, idx2, nnz2,
        nptr, (float4*)(ws + 640000), 227500, bh, cnt2, cnt1e, cnt1n, nblk);

    // 2) scans: ptr2 | ptr1e | ptr1n
    scans3<<<3, 256, 0, stream>>>(cnt2, ptr2, cnt1e, ptr1e, cnt1n, ptr1n);

    // 3) scan_blocks | fill_both
    sb_fb<<<16 + (nnz1 + 255) / 256, 256, 0, stream>>>(
        ptr2, bh, nblk, idx1, nnz1, ptr1e, fill1e, nodelist1,
        ptr1n, fill1n, edgelist1);

    // 4) scale-2 placement
    place_entries<<<nblk, 256, 0, stream>>>(idx2, nnz2, bh, nodelist2);

    // 5) edge gathers (64ch half-wave): s2 seg sums | s1 per-edge mean
    edge_gather<<<segB + N_EDGES / 8, 256, 0, stream>>>(
        nodelist2, ptr2, nnz2, xtP2u, esum2f, segB,
        nodelist1, ptr1e, xtP1u, emean1b);

    // 6) s2 mean + pack
    pack2<<<(N_EDGES * 32) / 256, 256, 0, stream>>>(esum2f, ptr2, emean2b);

    // 7) node gathers (64ch half-wave, atomic into o64)
    node_gather<<<segB + N_NODES / 8, 256, 0, stream>>>(
        idx2 + nnz2, nptr, nnz2, emean2b, o64, segB,
        edgelist1, ptr1n, emean1b);

    // 8) final bias-add + convert
    final_out<<<(N_NODES * 32) / 256, 256, 0, stream>>>(o64, bo, d_out,
                                                        (const unsigned int*)x);
}

// Round 12
// 253.438 us; speedup vs baseline: 1.1429x; 1.1429x over previous
//
#include <hip/hip_runtime.h>
#include <hip/hip_bf16.h>

// Problem constants (fixed by the reference's setup_inputs)
#define N_NODES 10000
#define N_EDGES 4000
#define IN_CH   128
#define HOC     128   // HEADS*OUT_CH (internal width of W1/W2)
#define OUT_CH  64    // folded gather width = OUT_CH
#define CHUNK   16384 // entries per counting-sort block (scale-2)
#define SEG     256   // entries per gather wave-segment (scale-2)

#define G_GEMM  625   // N_NODES/16
#define G_ZERO  512
#define G_NPTR  40    // ceil(10001/256)

__device__ __forceinline__ float bf2f(unsigned short u) {
    union { unsigned int i; float f; } v;
    v.i = ((unsigned int)u) << 16;
    return v.f;
}
__device__ __forceinline__ unsigned short f2bfu(float f) {
    union { __hip_bfloat16 h; unsigned short u; } v;
    v.h = __float2bfloat16(f);
    return v.u;
}

// load 8 consecutive float values from either fp32 or packed-bf16 storage.
__device__ __forceinline__ void load8(const void* base, size_t eoff, int isf32,
                                      float o[8]) {
    if (isf32) {
        const float4* q = (const float4*)((const float*)base + eoff);
        float4 a = q[0], b = q[1];
        o[0]=a.x; o[1]=a.y; o[2]=a.z; o[3]=a.w;
        o[4]=b.x; o[5]=b.y; o[6]=b.z; o[7]=b.w;
    } else {
        uint4 v = *(const uint4*)((const unsigned short*)base + eoff);
        const unsigned short* pv = (const unsigned short*)&v;
#pragma unroll
        for (int q = 0; q < 8; q++) o[q] = bf2f(pv[q]);
    }
}

__device__ __forceinline__ float loadS(const void* base, int i, int isf32) {
    return isf32 ? ((const float*)base)[i] : bf2f(((const unsigned short*)base)[i]);
}

// Per-wave inline dtype probe of x's first 512 bytes. 1 = fp32, 0 = bf16.
__device__ __forceinline__ int probe_isf32(const unsigned int* __restrict__ x) {
    const int lane = threadIdx.x & 63;
    unsigned int w0 = x[lane * 2], w1 = x[lane * 2 + 1];
    int h = 0, z = 0;
    {
        unsigned int lo = w0 & 0xFFFFu;
        if (lo == 0u) z++; else if (((lo >> 7) & 0xFF) >= 0x90u) h++;
        lo = w1 & 0xFFFFu;
        if (lo == 0u) z++; else if (((lo >> 7) & 0xFF) >= 0x90u) h++;
    }
    unsigned long long bh = __ballot(h > 0);
    unsigned long long bz = __ballot(z == 2);
    return (__popcll(bh) > 8 || __popcll(bz) > 50) ? 1 : 0;
}

// add 4 bf16 channels (one uint2) into acc[4]
__device__ __forceinline__ void add4(float acc[4], uint2 u) {
    acc[0] += bf2f((unsigned short)(u.x & 0xFFFFu));
    acc[1] += bf2f((unsigned short)(u.x >> 16));
    acc[2] += bf2f((unsigned short)(u.y & 0xFFFFu));
    acc[3] += bf2f((unsigned short)(u.y >> 16));
}

// cross-sub reduce (4 subs share channel quad ch4) + single atomic flush
__device__ __forceinline__ void flushq(float acc[4], float* __restrict__ dst,
                                       int g, int ch4, int sub) {
#pragma unroll
    for (int q = 0; q < 4; q++) {
        acc[q] += __shfl_xor(acc[q], 16);
        acc[q] += __shfl_xor(acc[q], 32);
    }
    if (sub == 0) {
        float* p = dst + (size_t)g * 64 + ch4 * 4;
        unsafeAtomicAdd(p + 0, acc[0]);
        unsafeAtomicAdd(p + 1, acc[1]);
        unsafeAtomicAdd(p + 2, acc[2]);
        unsafeAtomicAdd(p + 3, acc[3]);
    }
#pragma unroll
    for (int q = 0; q < 4; q++) acc[q] = 0.f;
}

// ---------------------------------------------------------------------------
// Dispatch 0: W_eff_s = 0.5*Wout@W_s (64x128), beff_s = 0.5*Wout@b_s, and
// zero the 18000-int count block. Blocks 0/1 = scales; block 2 = zero.
__global__ __launch_bounds__(256) void weff_zero(
    const void* __restrict__ Wout,
    const void* __restrict__ W1, const void* __restrict__ b1,
    const void* __restrict__ W2, const void* __restrict__ b2,
    float* __restrict__ weff1, float* __restrict__ beff1,
    float* __restrict__ weff2, float* __restrict__ beff2,
    int* __restrict__ cntz, const unsigned int* __restrict__ xprobe)
{
    if (blockIdx.x == 2) {
        for (int t = threadIdx.x; t < 18000; t += 256) cntz[t] = 0;
        return;
    }
    const int s = blockIdx.x;
    const void* Ws = s ? W2 : W1;
    const void* bs = s ? b2 : b1;
    float* outW = s ? weff2 : weff1;
    float* outb = s ? beff2 : beff1;
    const int isf32 = probe_isf32(xprobe);

    __shared__ float wsh[64][IN_CH];     // 32 KB: 64 rows of W_s at a time
    const int o  = threadIdx.x >> 2;       // 0..63 output row
    const int i0 = (threadIdx.x & 3) * 32; // column chunk
    float acc[32];
#pragma unroll
    for (int k = 0; k < 32; k++) acc[k] = 0.f;

    for (int pass = 0; pass < 2; pass++) {
        for (int r = 0; r < 4; r++) {
            int idx = r * 2048 + threadIdx.x * 8;
            float v[8];
            load8(Ws, (size_t)pass * 8192 + idx, isf32, v);
            float* d = &wsh[0][0] + idx;
#pragma unroll
            for (int q = 0; q < 8; q++) d[q] = v[q];
        }
        __syncthreads();
        for (int h = 0; h < 64; h++) {
            float wo = loadS(Wout, o * 128 + pass * 64 + h, isf32);
            const float* wr = &wsh[h][i0];
#pragma unroll
            for (int k = 0; k < 32; k++) acc[k] += wo * wr[k];
        }
        __syncthreads();
    }
#pragma unroll
    for (int k = 0; k < 32; k++) outW[o * 128 + i0 + k] = 0.5f * acc[k];

    if (threadIdx.x < 64) {
        float a = 0.f;
        for (int h = 0; h < 128; h++)
            a += loadS(Wout, threadIdx.x * 128 + h, isf32) * loadS(bs, h, isf32);
        outb[threadIdx.x] = 0.5f * a;
    }
}

// ---------------------------------------------------------------------------
// MEGA-PREP: block-range fused, all roles mutually independent.
__global__ __launch_bounds__(256) void prep(
    const void* __restrict__ x,
    const float* __restrict__ weff1, const float* __restrict__ beff1,
    const float* __restrict__ weff2, const float* __restrict__ beff2,
    unsigned short* __restrict__ xtP1b, unsigned short* __restrict__ xtP2b,
    const int* __restrict__ idx1, int nnz1,
    const int* __restrict__ idx2, int nnz2,
    int* __restrict__ nptr, float4* __restrict__ zerobase, int zeroN4,
    int* __restrict__ bh, int* __restrict__ cnt2,
    int* __restrict__ cnt1e, int* __restrict__ cnt1n, int nblk)
{
    __shared__ __align__(16) char smem[40000];
    int b = blockIdx.x;

    if (b < nblk) {                     // ---- hist2 ----
        int* h = (int*)smem;
        for (int t = threadIdx.x; t < N_EDGES; t += 256) h[t] = 0;
        __syncthreads();
        const int lo = b * CHUNK;
        const int hi = min(nnz2, lo + CHUNK);
        for (int i = lo + threadIdx.x; i < hi; i += 256)
            atomicAdd(&h[idx2[nnz2 + i]], 1);
        __syncthreads();
        int* dst = bh + (size_t)b * N_EDGES;
        for (int t = threadIdx.x; t < N_EDGES; t += 256) {
            int v = h[t];
            dst[t] = v;
            if (v) atomicAdd(&cnt2[t], v);
        }
        return;
    }
    b -= nblk;

    if (b < 8) {                        // ---- hist1 ----
        const int isEdge = b < 4;
        const int bid = isEdge ? b : (b - 4);
        const int nb = isEdge ? N_EDGES : N_NODES;
        const int* src = isEdge ? (idx1 + nnz1) : idx1;
        int* dst = isEdge ? cnt1e : cnt1n;
        int* h = (int*)smem;
        for (int t = threadIdx.x; t < nb; t += 256) h[t] = 0;
        __syncthreads();
        for (int i = bid * 256 + threadIdx.x; i < nnz1; i += 4 * 256)
            atomicAdd(&h[src[i]], 1);
        __syncthreads();
        for (int t = threadIdx.x; t < nb; t += 256) {
            int v = h[t];
            if (v) atomicAdd(&dst[t], v);
        }
        return;
    }
    b -= 8;

    if (b < G_GEMM) {                   // ---- gemm (64-col folded) ----
        const int isf32 = probe_isf32((const unsigned int*)x);
        float (*xs)[IN_CH] = (float (*)[IN_CH])smem;
        const int n0 = b * 16;
        {
            float v[8];
            load8(x, (size_t)n0 * IN_CH + (size_t)threadIdx.x * 8, isf32, v);
            float* dst = &xs[0][0] + threadIdx.x * 8;
#pragma unroll
            for (int q = 0; q < 8; q++) dst[q] = v[q];
        }
        __syncthreads();

        const int g   = threadIdx.x >> 7;      // node half
        const int sel = (threadIdx.x >> 6) & 1;
        const int j   = threadIdx.x & 63;      // output column
        const float* WE = sel ? weff2 : weff1;
        const float* BE = sel ? beff2 : beff1;
        unsigned short* xtP = sel ? xtP2b : xtP1b;

        float acc[8];
#pragma unroll
        for (int m = 0; m < 8; m++) acc[m] = 0.f;

        const float4* Wr = (const float4*)(WE + (size_t)j * 128);
        for (int kk = 0; kk < 16; kk++) {
            float4 a = Wr[kk * 2], c = Wr[kk * 2 + 1];
            float w[8] = {a.x, a.y, a.z, a.w, c.x, c.y, c.z, c.w};
#pragma unroll
            for (int m = 0; m < 8; m++) {
                const float* xr = &xs[g * 8 + m][kk * 8];
                acc[m] += xr[0]*w[0] + xr[1]*w[1] + xr[2]*w[2] + xr[3]*w[3]
                        + xr[4]*w[4] + xr[5]*w[5] + xr[6]*w[6] + xr[7]*w[7];
            }
        }
        const float bias = BE[j];
#pragma unroll
        for (int m = 0; m < 8; m++)
            xtP[(size_t)(n0 + g * 8 + m) * 64 + j] = f2bfu(acc[m] + bias);
        return;
    }
    b -= G_GEMM;

    if (b < G_ZERO) {                   // ---- zero ----
        for (int t = b * 256 + threadIdx.x; t < zeroN4; t += G_ZERO * 256)
            zerobase[t] = make_float4(0.f, 0.f, 0.f, 0.f);
        return;
    }
    b -= G_ZERO;

    {                                   // ---- nptr ----
        int n = b * 256 + threadIdx.x;
        if (n > N_NODES) return;
        int lo = 0, hi = nnz2;
        while (lo < hi) { int mid = (lo + hi) >> 1; if (idx2[mid] < n) lo = mid + 1; else hi = mid; }
        nptr[n] = lo;
    }
}

// ---------------------------------------------------------------------------
// 3-block exclusive scans over the count arrays.
__global__ __launch_bounds__(256) void scans3(
    const int* __restrict__ cnt2, int* __restrict__ ptr2,
    const int* __restrict__ cnt1e, int* __restrict__ ptr1e,
    const int* __restrict__ cnt1n, int* __restrict__ ptr1n)
{
    const int* cnt; int* ptr; int nb;
    if (blockIdx.x == 0)      { cnt = cnt2;  ptr = ptr2;  nb = N_EDGES; }
    else if (blockIdx.x == 1) { cnt = cnt1e; ptr = ptr1e; nb = N_EDGES; }
    else                      { cnt = cnt1n; ptr = ptr1n; nb = N_NODES; }
    __shared__ int part[256];
    const int t = threadIdx.x;
    const int K = (nb + 255) >> 8;
    const int base = t * K;
    int s = 0;
    for (int q = 0; q < K; q++) {
        int i = base + q;
        s += (i < nb) ? cnt[i] : 0;
    }
    part[t] = s;
    __syncthreads();
    for (int d = 1; d < 256; d <<= 1) {
        int v = (t >= d) ? part[t - d] : 0;
        __syncthreads();
        part[t] += v;
        __syncthreads();
    }
    int run = part[t] - s;
    for (int q = 0; q < K; q++) {
        int i = base + q;
        if (i < nb) { ptr[i] = run; run += cnt[i]; }
    }
    if (t == 255) ptr[nb] = part[255];
}

// ---------------------------------------------------------------------------
// Fused: scan_blocks + fill_both
__global__ __launch_bounds__(256) void sb_fb(
    const int* __restrict__ ptr2, int* __restrict__ bh, int nblk,
    const int* __restrict__ idx1, int nnz1,
    const int* __restrict__ ptr1e, int* __restrict__ fill1e,
    unsigned short* __restrict__ nodelist1,
    const int* __restrict__ ptr1n, int* __restrict__ fill1n,
    unsigned short* __restrict__ edgelist1)
{
    int b = blockIdx.x;
    if (b < 16) {
        int e = b * 256 + threadIdx.x;
        if (e >= N_EDGES) return;
        int run = ptr2[e];
        for (int k = 0; k < nblk; k++) {
            int i = k * N_EDGES + e;
            int t = bh[i];
            bh[i] = run;
            run += t;
        }
        return;
    }
    b -= 16;
    int i = b * 256 + threadIdx.x;
    if (i >= nnz1) return;
    int n = idx1[i];
    int e = idx1[nnz1 + i];
    int se = atomicAdd(&fill1e[e], 1);
    nodelist1[ptr1e[e] + se] = (unsigned short)n;
    int sn = atomicAdd(&fill1n[n], 1);
    edgelist1[ptr1n[n] + sn] = (unsigned short)e;
}

// ---------------------------------------------------------------------------
// scale-2 placement with LDS slot counters
__global__ __launch_bounds__(256) void place_entries(
    const int* __restrict__ idx, int nnz, const int* __restrict__ bh,
    unsigned short* __restrict__ nodelist)
{
    __shared__ int lh[N_EDGES];
    for (int t = threadIdx.x; t < N_EDGES; t += 256) lh[t] = 0;
    __syncthreads();
    const int b = blockIdx.x;
    const int lo = b * CHUNK;
    const int hi = min(nnz, lo + CHUNK);
    const int* bhb = bh + (size_t)b * N_EDGES;
    for (int i = lo + threadIdx.x; i < hi; i += 256) {
        int n = idx[i];
        int e = idx[nnz + i];
        int s = atomicAdd(&lh[e], 1);
        nodelist[bhb[e] + s] = (unsigned short)n;
    }
}

// ---------------------------------------------------------------------------
// Fused edge gathers, 64 channels.
//  [0, segB): s2 QUAD-entry segment gather (wave = 4 entries/load, uint2/lane)
//  [segB, segB+500): s1 half-wave-per-edge mean (fused div+pack)
__global__ __launch_bounds__(256) void edge_gather(
    const unsigned short* __restrict__ nodelist2, const int* __restrict__ ptr2,
    int nnz2, const unsigned int* __restrict__ xtP2u, float* __restrict__ esum2f,
    int segB,
    const unsigned short* __restrict__ nodelist1, const int* __restrict__ ptr1e,
    const unsigned int* __restrict__ xtP1u, unsigned int* __restrict__ emean1b)
{
    int b = blockIdx.x;
    if (b < segB) {
        const int lane = threadIdx.x & 63;
        const int sub  = lane >> 4;    // entry-in-quad
        const int ch4  = lane & 15;    // uint2 channel quad
        const int wave = (b * 256 + threadIdx.x) >> 6;
        const int s = wave * SEG;
        if (s >= nnz2) return;
        const int e_end = min(nnz2, s + SEG);
        const uint2* src2 = (const uint2*)xtP2u;

        int lo = 0, hi = N_EDGES;
        while (lo < hi) { int mid = (lo + hi) >> 1; if (ptr2[mid] <= s) lo = mid + 1; else hi = mid; }
        int g = lo - 1;
        int next = ptr2[g + 1];

        float acc[4] = {0.f, 0.f, 0.f, 0.f};
        for (int i = s; i < e_end; i += 64) {
            const int m = min(64, e_end - i);
            int vl = (i + lane < e_end) ? (int)nodelist2[i + lane] : 0;
            int j = 0;
            while (j < m) {
                while (i + j >= next) {
                    flushq(acc, esum2f, g, ch4, sub);
                    g++;
                    next = ptr2[g + 1];
                }
                int run = min(m - j, next - (i + j));
                int t = 0;
                for (; t + 15 < run; t += 16) {      // 4 indep quad loads
                    int n0 = __shfl(vl, j + t + sub);
                    int n1 = __shfl(vl, j + t + 4 + sub);
                    int n2 = __shfl(vl, j + t + 8 + sub);
                    int n3 = __shfl(vl, j + t + 12 + sub);
                    uint2 u0 = src2[(size_t)n0 * 16 + ch4];
                    uint2 u1 = src2[(size_t)n1 * 16 + ch4];
                    uint2 u2 = src2[(size_t)n2 * 16 + ch4];
                    uint2 u3 = src2[(size_t)n3 * 16 + ch4];
                    add4(acc, u0); add4(acc, u1); add4(acc, u2); add4(acc, u3);
                }
                for (; t + 3 < run; t += 4) {
                    int n0 = __shfl(vl, j + t + sub);
                    uint2 u0 = src2[(size_t)n0 * 16 + ch4];
                    add4(acc, u0);
                }
                if (t < run) {                        // tail: 1..3 entries
                    int r = run - t;
                    int n0 = __shfl(vl, j + t + (sub < r ? sub : r - 1));
                    uint2 u0 = src2[(size_t)n0 * 16 + ch4];
                    if (sub < r) add4(acc, u0);
                }
                j += run;
            }
        }
        flushq(acc, esum2f, g, ch4, sub);
        return;
    }
    b -= segB;
    {   // scale-1 half-wave-per-edge mean
        const int lane = threadIdx.x & 31;
        const int e = b * 8 + (threadIdx.x >> 5);
        const int lo = ptr1e[e], hi = ptr1e[e + 1];
        float accx = 0.f, accy = 0.f;
        for (int base = lo; base < hi; base += 32) {
            const int m = min(32, hi - base);
            int vl = (base + lane < hi) ? (int)nodelist1[base + lane] : 0;
            int t = 0;
            for (; t + 7 < m; t += 8) {
                int nn[8]; unsigned int uu[8];
#pragma unroll
                for (int q = 0; q < 8; q++) nn[q] = __shfl(vl, t + q, 32);
#pragma unroll
                for (int q = 0; q < 8; q++) uu[q] = xtP1u[nn[q] * 32 + lane];
#pragma unroll
                for (int q = 0; q < 8; q++) {
                    accx += bf2f((unsigned short)(uu[q] & 0xFFFFu));
                    accy += bf2f((unsigned short)(uu[q] >> 16));
                }
            }
            for (; t < m; t++) {
                int n = __shfl(vl, t, 32);
                unsigned int u = xtP1u[n * 32 + lane];
                accx += bf2f((unsigned short)(u & 0xFFFFu));
                accy += bf2f((unsigned short)(u >> 16));
            }
        }
        const float inv = 1.f / fmaxf((float)(hi - lo), 1.f);
        emean1b[e * 32 + lane] =
            ((unsigned int)f2bfu(accy * inv) << 16) | f2bfu(accx * inv);
    }
}

// ---------------------------------------------------------------------------
// s2 mean + pack to bf16x2 (counts from ptr2 diffs); 4000x32 uints
__global__ __launch_bounds__(256) void pack2(
    const float* __restrict__ esum2f, const int* __restrict__ ptr2,
    unsigned int* __restrict__ emean2b)
{
    int t = blockIdx.x * 256 + threadIdx.x;   // t < N_EDGES*32
    int e = t >> 5;
    float inv = 1.f / fmaxf((float)(ptr2[e + 1] - ptr2[e]), 1.f);
    float2 v = *(const float2*)(esum2f + (size_t)t * 2);
    emean2b[t] = ((unsigned int)f2bfu(v.y * inv) << 16) | f2bfu(v.x * inv);
}

// ---------------------------------------------------------------------------
// Fused node gathers into zeroed o64 (both scales atomic):
//  [0, segB): s2 QUAD-entry segment gather; [segB, +1250): s1 half-wave/node.
__global__ __launch_bounds__(256) void node_gather(
    const int* __restrict__ vals2, const int* __restrict__ nptr, int nnz2,
    const unsigned int* __restrict__ emean2b, float* __restrict__ o64, int segB,
    const unsigned short* __restrict__ edgelist1, const int* __restrict__ ptr1n,
    const unsigned int* __restrict__ emean1b)
{
    int b = blockIdx.x;
    if (b < segB) {
        const int lane = threadIdx.x & 63;
        const int sub  = lane >> 4;
        const int ch4  = lane & 15;
        const int wave = (b * 256 + threadIdx.x) >> 6;
        const int s = wave * SEG;
        if (s >= nnz2) return;
        const int e_end = min(nnz2, s + SEG);
        const uint2* src2 = (const uint2*)emean2b;

        int lo = 0, hi = N_NODES;
        while (lo < hi) { int mid = (lo + hi) >> 1; if (nptr[mid] <= s) lo = mid + 1; else hi = mid; }
        int g = lo - 1;
        int next = nptr[g + 1];

        float acc[4] = {0.f, 0.f, 0.f, 0.f};
        for (int i = s; i < e_end; i += 64) {
            const int m = min(64, e_end - i);
            int vl = (i + lane < e_end) ? vals2[i + lane] : 0;
            int j = 0;
            while (j < m) {
                while (i + j >= next) {
                    flushq(acc, o64, g, ch4, sub);
                    g++;
                    next = nptr[g + 1];
                }
                int run = min(m - j, next - (i + j));
                int t = 0;
                for (; t + 15 < run; t += 16) {
                    int e0 = __shfl(vl, j + t + sub);
                    int e1 = __shfl(vl, j + t + 4 + sub);
                    int e2 = __shfl(vl, j + t + 8 + sub);
                    int e3 = __shfl(vl, j + t + 12 + sub);
                    uint2 u0 = src2[(size_t)e0 * 16 + ch4];
                    uint2 u1 = src2[(size_t)e1 * 16 + ch4];
                    uint2 u2 = src2[(size_t)e2 * 16 + ch4];
                    uint2 u3 = src2[(size_t)e3 * 16 + ch4];
                    add4(acc, u0); add4(acc, u1); add4(acc, u2); add4(acc, u3);
                }
                for (; t + 3 < run; t += 4) {
                    int e0 = __shfl(vl, j + t + sub);
                    uint2 u0 = src2[(size_t)e0 * 16 + ch4];
                    add4(acc, u0);
                }
                if (t < run) {
                    int r = run - t;
                    int e0 = __shfl(vl, j + t + (sub < r ? sub : r - 1));
                    uint2 u0 = src2[(size_t)e0 * 16 + ch4];
                    if (sub < r) add4(acc, u0);
                }
                j += run;
            }
        }
        flushq(acc, o64, g, ch4, sub);
        return;
    }
    b -= segB;
    {   // scale-1 half-wave-per-node
        const int lane = threadIdx.x & 31;
        const int n = b * 8 + (threadIdx.x >> 5);
        const int lo = ptr1n[n], hi = ptr1n[n + 1];
        if (lo == hi) return;
        float accx = 0.f, accy = 0.f;
        for (int base = lo; base < hi; base += 32) {
            const int m = min(32, hi - base);
            int vl = (base + lane < hi) ? (int)edgelist1[base + lane] : 0;
            int t = 0;
            for (; t + 7 < m; t += 8) {
                int ee[8]; unsigned int uu[8];
#pragma unroll
                for (int q = 0; q < 8; q++) ee[q] = __shfl(vl, t + q, 32);
#pragma unroll
                for (int q = 0; q < 8; q++) uu[q] = emean1b[ee[q] * 32 + lane];
#pragma unroll
                for (int q = 0; q < 8; q++) {
                    accx += bf2f((unsigned short)(uu[q] & 0xFFFFu));
                    accy += bf2f((unsigned short)(uu[q] >> 16));
                }
            }
            for (; t < m; t++) {
                int e = __shfl(vl, t, 32);
                unsigned int u = emean1b[e * 32 + lane];
                accx += bf2f((unsigned short)(u & 0xFFFFu));
                accy += bf2f((unsigned short)(u >> 16));
            }
        }
        unsafeAtomicAdd(o64 + (size_t)n * 64 + 2 * lane,     accx);
        unsafeAtomicAdd(o64 + (size_t)n * 64 + 2 * lane + 1, accy);
    }
}

// ---------------------------------------------------------------------------
// final: out[n][c] = o64[n][c] + bout[c]   (projection already folded)
__global__ __launch_bounds__(256) void final_out(
    const float* __restrict__ o64, const void* __restrict__ bout,
    void* __restrict__ out, const unsigned int* __restrict__ xprobe)
{
    const int isf32 = probe_isf32(xprobe);
    int t = blockIdx.x * 256 + threadIdx.x;   // t < N_NODES*32
    int c = t & 31;
    float2 v = *(const float2*)(o64 + (size_t)t * 2);
    float r0 = v.x + loadS(bout, 2 * c, isf32);
    float r1 = v.y + loadS(bout, 2 * c + 1, isf32);
    if (isf32) ((float2*)out)[t] = make_float2(r0, r1);
    else ((unsigned int*)out)[t] = ((unsigned int)f2bfu(r1) << 16) | f2bfu(r0);
}

// ---------------------------------------------------------------------------
extern "C" void kernel_launch(void* const* d_in, const int* in_sizes, int n_in,
                              void* d_out, int out_size, void* d_ws, size_t ws_size,
                              hipStream_t stream)
{
    const void* x  = d_in[0];
    const int* idx1 = (const int*)d_in[1];
    const int* idx2 = (const int*)d_in[2];
    const void* W1 = d_in[3];
    const void* b1 = d_in[4];
    const void* W2 = d_in[5];
    const void* b2 = d_in[6];
    const void* Wo = d_in[7];
    const void* bo = d_in[8];

    const int nnz1 = in_sizes[1] / 2;
    const int nnz2 = in_sizes[2] / 2;
    const int nblk = (nnz2 + CHUNK - 1) / CHUNK;

    // ---- workspace layout (units of 4 bytes) ----
    float* ws = (float*)d_ws;
    unsigned short* xtP1b = (unsigned short*)ws;              // [0 .. 320,000)
    unsigned int*   xtP1u = (unsigned int*)xtP1b;
    unsigned short* xtP2b = (unsigned short*)(ws + 320000);   // [.. 640,000)
    unsigned int*   xtP2u = (unsigned int*)xtP2b;
    float* o64    = ws + 640000;            // 640,000   --- zero span start
    int*   fill1e = (int*)(ws + 1280000);   //   4,000
    int*   fill1n = (int*)(ws + 1284000);   //  10,000
    float* esum2f = ws + 1294000;           // 256,000   --- zero span end
    // zero span: [640,000 .. 1,550,000) = 910,000 floats = 227,500 f4
    int* cnt2  = (int*)(ws + 1550000);      //  4,000  --- int-zero span (18,000)
    int* cnt1e = (int*)(ws + 1554000);      //  4,000
    int* cnt1n = (int*)(ws + 1558000);      // 10,000
    int* ptr2  = (int*)(ws + 1568000);      //  4,001
    int* ptr1e = (int*)(ws + 1572004);      //  4,001
    int* ptr1n = (int*)(ws + 1576008);      // 10,001
    int* nptr  = (int*)(ws + 1586012);      // 10,001
    float* weff1 = ws + 1596016;            //  8,192
    float* weff2 = ws + 1604208;            //  8,192
    float* beff1 = ws + 1612400;            //     64
    float* beff2 = ws + 1612464;            //     64
    unsigned int* emean2b = (unsigned int*)(ws + 1612528);   // 128,000
    unsigned int* emean1b = (unsigned int*)(ws + 1740528);   // 128,000
    unsigned short* nodelist2 = (unsigned short*)(ws + 1868528);
    const size_t nl2u = ((size_t)nnz2 + 1) / 2;
    unsigned short* nodelist1 = (unsigned short*)(ws + 1868528 + nl2u);
    const size_t nl1u = ((size_t)nnz1 + 1) / 2;
    unsigned short* edgelist1 = (unsigned short*)(ws + 1868528 + nl2u + nl1u);
    const size_t bh_off = (1868528 + nl2u + 2 * nl1u + 7) & ~(size_t)7;
    int* bh = (int*)(ws + bh_off);

    const int segB = ((nnz2 + SEG - 1) / SEG + 3) / 4;   // waves/4 per block

    // 0) W_eff precompute + zero count arrays
    weff_zero<<<3, 256, 0, stream>>>(Wo, W1, b1, W2, b2,
                                     weff1, beff1, weff2, beff2,
                                     cnt2, (const unsigned int*)x);

    // 1) mega-prep: hist2 | hist1 | gemm(64) | zero | nptr
    prep<<<nblk + 8 + G_GEMM + G_ZERO + G_NPTR, 256, 0, stream>>>(
        x, weff1, beff1, weff2, beff2, xtP1b, xtP2b,
        idx1, nnz1, idx2, nnz2,
        nptr, (float4*)(ws + 640000), 227500, bh, cnt2, cnt1e, cnt1n, nblk);

    // 2) scans: ptr2 | ptr1e | ptr1n
    scans3<<<3, 256, 0, stream>>>(cnt2, ptr2, cnt1e, ptr1e, cnt1n, ptr1n);

    // 3) scan_blocks | fill_both
    sb_fb<<<16 + (nnz1 + 255) / 256, 256, 0, stream>>>(
        ptr2, bh, nblk, idx1, nnz1, ptr1e, fill1e, nodelist1,
        ptr1n, fill1n, edgelist1);

    // 4) scale-2 placement
    place_entries<<<nblk, 256, 0, stream>>>(idx2, nnz2, bh, nodelist2);

    // 5) edge gathers: s2 quad-entry seg sums | s1 per-edge mean
    edge_gather<<<segB + N_EDGES / 8, 256, 0, stream>>>(
        nodelist2, ptr2, nnz2, xtP2u, esum2f, segB,
        nodelist1, ptr1e, xtP1u, emean1b);

    // 6) s2 mean + pack
    pack2<<<(N_EDGES * 32) / 256, 256, 0, stream>>>(esum2f, ptr2, emean2b);

    // 7) node gathers: s2 quad-entry seg sums | s1 per-node (atomic into o64)
    node_gather<<<segB + N_NODES / 8, 256, 0, stream>>>(
        idx2 + nnz2, nptr, nnz2, emean2b, o64, segB,
        edgelist1, ptr1n, emean1b);

    // 8) final bias-add + convert
    final_out<<<(N_NODES * 32) / 256, 256, 0, stream>>>(o64, bo, d_out,
                                                        (const unsigned int*)x);
}

// Round 13
// 240.021 us; speedup vs baseline: 1.2067x; 1.0559x over previous
//
#include <hip/hip_runtime.h>
#include <hip/hip_bf16.h>

// Problem constants (fixed by the reference's setup_inputs)
#define N_NODES 10000
#define N_EDGES 4000
#define IN_CH   128
#define HOC     128   // HEADS*OUT_CH (internal width of W1/W2)
#define OUT_CH  64    // folded gather width = OUT_CH
#define CHUNK   16384 // entries per counting-sort block (scale-2)
#define SEG     256   // entries per gather wave-segment (scale-2)

#define G_GEMM  625   // N_NODES/16
#define G_ZERO  512
#define G_NPTR  40    // ceil(10001/256)

__device__ __forceinline__ float bf2f(unsigned short u) {
    union { unsigned int i; float f; } v;
    v.i = ((unsigned int)u) << 16;
    return v.f;
}
__device__ __forceinline__ unsigned short f2bfu(float f) {
    union { __hip_bfloat16 h; unsigned short u; } v;
    v.h = __float2bfloat16(f);
    return v.u;
}

// load 8 consecutive float values from either fp32 or packed-bf16 storage.
__device__ __forceinline__ void load8(const void* base, size_t eoff, int isf32,
                                      float o[8]) {
    if (isf32) {
        const float4* q = (const float4*)((const float*)base + eoff);
        float4 a = q[0], b = q[1];
        o[0]=a.x; o[1]=a.y; o[2]=a.z; o[3]=a.w;
        o[4]=b.x; o[5]=b.y; o[6]=b.z; o[7]=b.w;
    } else {
        uint4 v = *(const uint4*)((const unsigned short*)base + eoff);
        const unsigned short* pv = (const unsigned short*)&v;
#pragma unroll
        for (int q = 0; q < 8; q++) o[q] = bf2f(pv[q]);
    }
}

__device__ __forceinline__ float loadS(const void* base, int i, int isf32) {
    return isf32 ? ((const float*)base)[i] : bf2f(((const unsigned short*)base)[i]);
}

// Per-wave inline dtype probe of x's first 512 bytes. 1 = fp32, 0 = bf16.
__device__ __forceinline__ int probe_isf32(const unsigned int* __restrict__ x) {
    const int lane = threadIdx.x & 63;
    unsigned int w0 = x[lane * 2], w1 = x[lane * 2 + 1];
    int h = 0, z = 0;
    {
        unsigned int lo = w0 & 0xFFFFu;
        if (lo == 0u) z++; else if (((lo >> 7) & 0xFF) >= 0x90u) h++;
        lo = w1 & 0xFFFFu;
        if (lo == 0u) z++; else if (((lo >> 7) & 0xFF) >= 0x90u) h++;
    }
    unsigned long long bh = __ballot(h > 0);
    unsigned long long bz = __ballot(z == 2);
    return (__popcll(bh) > 8 || __popcll(bz) > 50) ? 1 : 0;
}

// add 4 bf16 channels (one uint2) into acc[4]
__device__ __forceinline__ void add4(float acc[4], uint2 u) {
    acc[0] += bf2f((unsigned short)(u.x & 0xFFFFu));
    acc[1] += bf2f((unsigned short)(u.x >> 16));
    acc[2] += bf2f((unsigned short)(u.y & 0xFFFFu));
    acc[3] += bf2f((unsigned short)(u.y >> 16));
}

// cross-sub reduce (4 subs share channel quad ch4) + single atomic flush
__device__ __forceinline__ void flushq(float acc[4], float* __restrict__ dst,
                                       int g, int ch4, int sub) {
#pragma unroll
    for (int q = 0; q < 4; q++) {
        acc[q] += __shfl_xor(acc[q], 16);
        acc[q] += __shfl_xor(acc[q], 32);
    }
    if (sub == 0) {
        float* p = dst + (size_t)g * 64 + ch4 * 4;
        unsafeAtomicAdd(p + 0, acc[0]);
        unsafeAtomicAdd(p + 1, acc[1]);
        unsafeAtomicAdd(p + 2, acc[2]);
        unsafeAtomicAdd(p + 3, acc[3]);
    }
#pragma unroll
    for (int q = 0; q < 4; q++) acc[q] = 0.f;
}

// ---------------------------------------------------------------------------
// Dispatch 0: W_eff_s = 0.5*Wout@W_s (64x128), beff_s = 0.5*Wout@b_s, and
// zero the 18000-int count block. Blocks 0/1 = scales; block 2 = zero.
__global__ __launch_bounds__(256) void weff_zero(
    const void* __restrict__ Wout,
    const void* __restrict__ W1, const void* __restrict__ b1,
    const void* __restrict__ W2, const void* __restrict__ b2,
    float* __restrict__ weff1, float* __restrict__ beff1,
    float* __restrict__ weff2, float* __restrict__ beff2,
    int* __restrict__ cntz, const unsigned int* __restrict__ xprobe)
{
    if (blockIdx.x == 2) {
        for (int t = threadIdx.x; t < 18000; t += 256) cntz[t] = 0;
        return;
    }
    const int s = blockIdx.x;
    const void* Ws = s ? W2 : W1;
    const void* bs = s ? b2 : b1;
    float* outW = s ? weff2 : weff1;
    float* outb = s ? beff2 : beff1;
    const int isf32 = probe_isf32(xprobe);

    __shared__ float wsh[64][IN_CH];     // 32 KB: 64 rows of W_s at a time
    const int o  = threadIdx.x >> 2;       // 0..63 output row
    const int i0 = (threadIdx.x & 3) * 32; // column chunk
    float acc[32];
#pragma unroll
    for (int k = 0; k < 32; k++) acc[k] = 0.f;

    for (int pass = 0; pass < 2; pass++) {
        for (int r = 0; r < 4; r++) {
            int idx = r * 2048 + threadIdx.x * 8;
            float v[8];
            load8(Ws, (size_t)pass * 8192 + idx, isf32, v);
            float* d = &wsh[0][0] + idx;
#pragma unroll
            for (int q = 0; q < 8; q++) d[q] = v[q];
        }
        __syncthreads();
        for (int h = 0; h < 64; h++) {
            float wo = loadS(Wout, o * 128 + pass * 64 + h, isf32);
            const float* wr = &wsh[h][i0];
#pragma unroll
            for (int k = 0; k < 32; k++) acc[k] += wo * wr[k];
        }
        __syncthreads();
    }
#pragma unroll
    for (int k = 0; k < 32; k++) outW[o * 128 + i0 + k] = 0.5f * acc[k];

    if (threadIdx.x < 64) {
        float a = 0.f;
        for (int h = 0; h < 128; h++)
            a += loadS(Wout, threadIdx.x * 128 + h, isf32) * loadS(bs, h, isf32);
        outb[threadIdx.x] = 0.5f * a;
    }
}

// ---------------------------------------------------------------------------
// MEGA-PREP: block-range fused, all roles mutually independent.
__global__ __launch_bounds__(256) void prep(
    const void* __restrict__ x,
    const float* __restrict__ weff1, const float* __restrict__ beff1,
    const float* __restrict__ weff2, const float* __restrict__ beff2,
    unsigned short* __restrict__ xtP1b, unsigned short* __restrict__ xtP2b,
    const int* __restrict__ idx1, int nnz1,
    const int* __restrict__ idx2, int nnz2,
    int* __restrict__ nptr, float4* __restrict__ zerobase, int zeroN4,
    int* __restrict__ bh, int* __restrict__ cnt2,
    int* __restrict__ cnt1e, int* __restrict__ cnt1n, int nblk)
{
    __shared__ __align__(16) char smem[40000];
    int b = blockIdx.x;

    if (b < nblk) {                     // ---- hist2 ----
        int* h = (int*)smem;
        for (int t = threadIdx.x; t < N_EDGES; t += 256) h[t] = 0;
        __syncthreads();
        const int lo = b * CHUNK;
        const int hi = min(nnz2, lo + CHUNK);
        for (int i = lo + threadIdx.x; i < hi; i += 256)
            atomicAdd(&h[idx2[nnz2 + i]], 1);
        __syncthreads();
        int* dst = bh + (size_t)b * N_EDGES;
        for (int t = threadIdx.x; t < N_EDGES; t += 256) {
            int v = h[t];
            dst[t] = v;
            if (v) atomicAdd(&cnt2[t], v);
        }
        return;
    }
    b -= nblk;

    if (b < 8) {                        // ---- hist1 ----
        const int isEdge = b < 4;
        const int bid = isEdge ? b : (b - 4);
        const int nb = isEdge ? N_EDGES : N_NODES;
        const int* src = isEdge ? (idx1 + nnz1) : idx1;
        int* dst = isEdge ? cnt1e : cnt1n;
        int* h = (int*)smem;
        for (int t = threadIdx.x; t < nb; t += 256) h[t] = 0;
        __syncthreads();
        for (int i = bid * 256 + threadIdx.x; i < nnz1; i += 4 * 256)
            atomicAdd(&h[src[i]], 1);
        __syncthreads();
        for (int t = threadIdx.x; t < nb; t += 256) {
            int v = h[t];
            if (v) atomicAdd(&dst[t], v);
        }
        return;
    }
    b -= 8;

    if (b < G_GEMM) {                   // ---- gemm (64-col folded) ----
        const int isf32 = probe_isf32((const unsigned int*)x);
        float (*xs)[IN_CH] = (float (*)[IN_CH])smem;
        const int n0 = b * 16;
        {
            float v[8];
            load8(x, (size_t)n0 * IN_CH + (size_t)threadIdx.x * 8, isf32, v);
            float* dst = &xs[0][0] + threadIdx.x * 8;
#pragma unroll
            for (int q = 0; q < 8; q++) dst[q] = v[q];
        }
        __syncthreads();

        const int g   = threadIdx.x >> 7;      // node half
        const int sel = (threadIdx.x >> 6) & 1;
        const int j   = threadIdx.x & 63;      // output column
        const float* WE = sel ? weff2 : weff1;
        const float* BE = sel ? beff2 : beff1;
        unsigned short* xtP = sel ? xtP2b : xtP1b;

        float acc[8];
#pragma unroll
        for (int m = 0; m < 8; m++) acc[m] = 0.f;

        const float4* Wr = (const float4*)(WE + (size_t)j * 128);
        for (int kk = 0; kk < 16; kk++) {
            float4 a = Wr[kk * 2], c = Wr[kk * 2 + 1];
            float w[8] = {a.x, a.y, a.z, a.w, c.x, c.y, c.z, c.w};
#pragma unroll
            for (int m = 0; m < 8; m++) {
                const float* xr = &xs[g * 8 + m][kk * 8];
                acc[m] += xr[0]*w[0] + xr[1]*w[1] + xr[2]*w[2] + xr[3]*w[3]
                        + xr[4]*w[4] + xr[5]*w[5] + xr[6]*w[6] + xr[7]*w[7];
            }
        }
        const float bias = BE[j];
#pragma unroll
        for (int m = 0; m < 8; m++)
            xtP[(size_t)(n0 + g * 8 + m) * 64 + j] = f2bfu(acc[m] + bias);
        return;
    }
    b -= G_GEMM;

    if (b < G_ZERO) {                   // ---- zero ----
        for (int t = b * 256 + threadIdx.x; t < zeroN4; t += G_ZERO * 256)
            zerobase[t] = make_float4(0.f, 0.f, 0.f, 0.f);
        return;
    }
    b -= G_ZERO;

    {                                   // ---- nptr ----
        int n = b * 256 + threadIdx.x;
        if (n > N_NODES) return;
        int lo = 0, hi = nnz2;
        while (lo < hi) { int mid = (lo + hi) >> 1; if (idx2[mid] < n) lo = mid + 1; else hi = mid; }
        nptr[n] = lo;
    }
}

// ---------------------------------------------------------------------------
// 3-block exclusive scans over the count arrays.
__global__ __launch_bounds__(256) void scans3(
    const int* __restrict__ cnt2, int* __restrict__ ptr2,
    const int* __restrict__ cnt1e, int* __restrict__ ptr1e,
    const int* __restrict__ cnt1n, int* __restrict__ ptr1n)
{
    const int* cnt; int* ptr; int nb;
    if (blockIdx.x == 0)      { cnt = cnt2;  ptr = ptr2;  nb = N_EDGES; }
    else if (blockIdx.x == 1) { cnt = cnt1e; ptr = ptr1e; nb = N_EDGES; }
    else                      { cnt = cnt1n; ptr = ptr1n; nb = N_NODES; }
    __shared__ int part[256];
    const int t = threadIdx.x;
    const int K = (nb + 255) >> 8;
    const int base = t * K;
    int s = 0;
    for (int q = 0; q < K; q++) {
        int i = base + q;
        s += (i < nb) ? cnt[i] : 0;
    }
    part[t] = s;
    __syncthreads();
    for (int d = 1; d < 256; d <<= 1) {
        int v = (t >= d) ? part[t - d] : 0;
        __syncthreads();
        part[t] += v;
        __syncthreads();
    }
    int run = part[t] - s;
    for (int q = 0; q < K; q++) {
        int i = base + q;
        if (i < nb) { ptr[i] = run; run += cnt[i]; }
    }
    if (t == 255) ptr[nb] = part[255];
}

// ---------------------------------------------------------------------------
// Fused: scan_blocks (batched-prefetch, breaks serial L2 chain) + fill_both
__global__ __launch_bounds__(256) void sb_fb(
    const int* __restrict__ ptr2, int* __restrict__ bh, int nblk,
    const int* __restrict__ idx1, int nnz1,
    const int* __restrict__ ptr1e, int* __restrict__ fill1e,
    unsigned short* __restrict__ nodelist1,
    const int* __restrict__ ptr1n, int* __restrict__ fill1n,
    unsigned short* __restrict__ edgelist1)
{
    int b = blockIdx.x;
    if (b < 16) {                       // scan_blocks: thread per edge
        int e = b * 256 + threadIdx.x;
        if (e >= N_EDGES) return;
        int run = ptr2[e];
        int k = 0;
        for (; k + 8 <= nblk; k += 8) {
            int v[8];
#pragma unroll
            for (int q = 0; q < 8; q++)
                v[q] = bh[(size_t)(k + q) * N_EDGES + e];   // 8 indep loads
#pragma unroll
            for (int q = 0; q < 8; q++) {
                bh[(size_t)(k + q) * N_EDGES + e] = run;
                run += v[q];
            }
        }
        for (; k < nblk; k++) {
            int i = k * N_EDGES + e;
            int t = bh[i];
            bh[i] = run;
            run += t;
        }
        return;
    }
    b -= 16;
    int i = b * 256 + threadIdx.x;
    if (i >= nnz1) return;
    int n = idx1[i];
    int e = idx1[nnz1 + i];
    int se = atomicAdd(&fill1e[e], 1);
    nodelist1[ptr1e[e] + se] = (unsigned short)n;
    int sn = atomicAdd(&fill1n[n], 1);
    edgelist1[ptr1n[n] + sn] = (unsigned short)e;
}

// ---------------------------------------------------------------------------
// scale-2 placement with LDS slot counters; 1024-thread blocks (16 waves) so
// each thread handles only 16 entries -> latency-hidden.
__global__ __launch_bounds__(1024) void place_entries(
    const int* __restrict__ idx, int nnz, const int* __restrict__ bh,
    unsigned short* __restrict__ nodelist)
{
    __shared__ int lh[N_EDGES];
    for (int t = threadIdx.x; t < N_EDGES; t += 1024) lh[t] = 0;
    __syncthreads();
    const int b = blockIdx.x;
    const int lo = b * CHUNK;
    const int hi = min(nnz, lo + CHUNK);
    const int* bhb = bh + (size_t)b * N_EDGES;
    for (int i = lo + threadIdx.x; i < hi; i += 1024) {
        int n = idx[i];
        int e = idx[nnz + i];
        int s = atomicAdd(&lh[e], 1);
        nodelist[bhb[e] + s] = (unsigned short)n;
    }
}

// ---------------------------------------------------------------------------
// Fused edge gathers, 64 channels.
//  [0, segB): s2 QUAD-entry segment gather (wave = 4 entries/load, uint2/lane)
//  [segB, segB+500): s1 half-wave-per-edge mean (fused div+pack)
__global__ __launch_bounds__(256) void edge_gather(
    const unsigned short* __restrict__ nodelist2, const int* __restrict__ ptr2,
    int nnz2, const unsigned int* __restrict__ xtP2u, float* __restrict__ esum2f,
    int segB,
    const unsigned short* __restrict__ nodelist1, const int* __restrict__ ptr1e,
    const unsigned int* __restrict__ xtP1u, unsigned int* __restrict__ emean1b)
{
    int b = blockIdx.x;
    if (b < segB) {
        const int lane = threadIdx.x & 63;
        const int sub  = lane >> 4;    // entry-in-quad
        const int ch4  = lane & 15;    // uint2 channel quad
        const int wave = (b * 256 + threadIdx.x) >> 6;
        const int s = wave * SEG;
        if (s >= nnz2) return;
        const int e_end = min(nnz2, s + SEG);
        const uint2* src2 = (const uint2*)xtP2u;

        int lo = 0, hi = N_EDGES;
        while (lo < hi) { int mid = (lo + hi) >> 1; if (ptr2[mid] <= s) lo = mid + 1; else hi = mid; }
        int g = lo - 1;
        int next = ptr2[g + 1];

        float acc[4] = {0.f, 0.f, 0.f, 0.f};
        for (int i = s; i < e_end; i += 64) {
            const int m = min(64, e_end - i);
            int vl = (i + lane < e_end) ? (int)nodelist2[i + lane] : 0;
            int j = 0;
            while (j < m) {
                while (i + j >= next) {
                    flushq(acc, esum2f, g, ch4, sub);
                    g++;
                    next = ptr2[g + 1];
                }
                int run = min(m - j, next - (i + j));
                int t = 0;
                for (; t + 15 < run; t += 16) {      // 4 indep quad loads
                    int n0 = __shfl(vl, j + t + sub);
                    int n1 = __shfl(vl, j + t + 4 + sub);
                    int n2 = __shfl(vl, j + t + 8 + sub);
                    int n3 = __shfl(vl, j + t + 12 + sub);
                    uint2 u0 = src2[(size_t)n0 * 16 + ch4];
                    uint2 u1 = src2[(size_t)n1 * 16 + ch4];
                    uint2 u2 = src2[(size_t)n2 * 16 + ch4];
                    uint2 u3 = src2[(size_t)n3 * 16 + ch4];
                    add4(acc, u0); add4(acc, u1); add4(acc, u2); add4(acc, u3);
                }
                for (; t + 3 < run; t += 4) {
                    int n0 = __shfl(vl, j + t + sub);
                    uint2 u0 = src2[(size_t)n0 * 16 + ch4];
                    add4(acc, u0);
                }
                if (t < run) {                        // tail: 1..3 entries
                    int r = run - t;
                    int n0 = __shfl(vl, j + t + (sub < r ? sub : r - 1));
                    uint2 u0 = src2[(size_t)n0 * 16 + ch4];
                    if (sub < r) add4(acc, u0);
                }
                j += run;
            }
        }
        flushq(acc, esum2f, g, ch4, sub);
        return;
    }
    b -= segB;
    {   // scale-1 half-wave-per-edge mean
        const int lane = threadIdx.x & 31;
        const int e = b * 8 + (threadIdx.x >> 5);
        const int lo = ptr1e[e], hi = ptr1e[e + 1];
        float accx = 0.f, accy = 0.f;
        for (int base = lo; base < hi; base += 32) {
            const int m = min(32, hi - base);
            int vl = (base + lane < hi) ? (int)nodelist1[base + lane] : 0;
            int t = 0;
            for (; t + 7 < m; t += 8) {
                int nn[8]; unsigned int uu[8];
#pragma unroll
                for (int q = 0; q < 8; q++) nn[q] = __shfl(vl, t + q, 32);
#pragma unroll
                for (int q = 0; q < 8; q++) uu[q] = xtP1u[nn[q] * 32 + lane];
#pragma unroll
                for (int q = 0; q < 8; q++) {
                    accx += bf2f((unsigned short)(uu[q] & 0xFFFFu));
                    accy += bf2f((unsigned short)(uu[q] >> 16));
                }
            }
            for (; t < m; t++) {
                int n = __shfl(vl, t, 32);
                unsigned int u = xtP1u[n * 32 + lane];
                accx += bf2f((unsigned short)(u & 0xFFFFu));
                accy += bf2f((unsigned short)(u >> 16));
            }
        }
        const float inv = 1.f / fmaxf((float)(hi - lo), 1.f);
        emean1b[e * 32 + lane] =
            ((unsigned int)f2bfu(accy * inv) << 16) | f2bfu(accx * inv);
    }
}

// ---------------------------------------------------------------------------
// s2 mean + pack to bf16x2 (counts from ptr2 diffs); 4000x32 uints
__global__ __launch_bounds__(256) void pack2(
    const float* __restrict__ esum2f, const int* __restrict__ ptr2,
    unsigned int* __restrict__ emean2b)
{
    int t = blockIdx.x * 256 + threadIdx.x;   // t < N_EDGES*32
    int e = t >> 5;
    float inv = 1.f / fmaxf((float)(ptr2[e + 1] - ptr2[e]), 1.f);
    float2 v = *(const float2*)(esum2f + (size_t)t * 2);
    emean2b[t] = ((unsigned int)f2bfu(v.y * inv) << 16) | f2bfu(v.x * inv);
}

// ---------------------------------------------------------------------------
// Fused node gathers into zeroed o64 (both scales atomic):
//  [0, segB): s2 QUAD-entry segment gather; [segB, +1250): s1 half-wave/node.
__global__ __launch_bounds__(256) void node_gather(
    const int* __restrict__ vals2, const int* __restrict__ nptr, int nnz2,
    const unsigned int* __restrict__ emean2b, float* __restrict__ o64, int segB,
    const unsigned short* __restrict__ edgelist1, const int* __restrict__ ptr1n,
    const unsigned int* __restrict__ emean1b)
{
    int b = blockIdx.x;
    if (b < segB) {
        const int lane = threadIdx.x & 63;
        const int sub  = lane >> 4;
        const int ch4  = lane & 15;
        const int wave = (b * 256 + threadIdx.x) >> 6;
        const int s = wave * SEG;
        if (s >= nnz2) return;
        const int e_end = min(nnz2, s + SEG);
        const uint2* src2 = (const uint2*)emean2b;

        int lo = 0, hi = N_NODES;
        while (lo < hi) { int mid = (lo + hi) >> 1; if (nptr[mid] <= s) lo = mid + 1; else hi = mid; }
        int g = lo - 1;
        int next = nptr[g + 1];

        float acc[4] = {0.f, 0.f, 0.f, 0.f};
        for (int i = s; i < e_end; i += 64) {
            const int m = min(64, e_end - i);
            int vl = (i + lane < e_end) ? vals2[i + lane] : 0;
            int j = 0;
            while (j < m) {
                while (i + j >= next) {
                    flushq(acc, o64, g, ch4, sub);
                    g++;
                    next = nptr[g + 1];
                }
                int run = min(m - j, next - (i + j));
                int t = 0;
                for (; t + 15 < run; t += 16) {
                    int e0 = __shfl(vl, j + t + sub);
                    int e1 = __shfl(vl, j + t + 4 + sub);
                    int e2 = __shfl(vl, j + t + 8 + sub);
                    int e3 = __shfl(vl, j + t + 12 + sub);
                    uint2 u0 = src2[(size_t)e0 * 16 + ch4];
                    uint2 u1 = src2[(size_t)e1 * 16 + ch4];
                    uint2 u2 = src2[(size_t)e2 * 16 + ch4];
                    uint2 u3 = src2[(size_t)e3 * 16 + ch4];
                    add4(acc, u0); add4(acc, u1); add4(acc, u2); add4(acc, u3);
                }
                for (; t + 3 < run; t += 4) {
                    int e0 = __shfl(vl, j + t + sub);
                    uint2 u0 = src2[(size_t)e0 * 16 + ch4];
                    add4(acc, u0);
                }
                if (t < run) {
                    int r = run - t;
                    int e0 = __shfl(vl, j + t + (sub < r ? sub : r - 1));
                    uint2 u0 = src2[(size_t)e0 * 16 + ch4];
                    if (sub < r) add4(acc, u0);
                }
                j += run;
            }
        }
        flushq(acc, o64, g, ch4, sub);
        return;
    }
    b -= segB;
    {   // scale-1 half-wave-per-node
        const int lane = threadIdx.x & 31;
        const int n = b * 8 + (threadIdx.x >> 5);
        const int lo = ptr1n[n], hi = ptr1n[n + 1];
        if (lo == hi) return;
        float accx = 0.f, accy = 0.f;
        for (int base = lo; base < hi; base += 32) {
            const int m = min(32, hi - base);
            int vl = (base + lane < hi) ? (int)edgelist1[base + lane] : 0;
            int t = 0;
            for (; t + 7 < m; t += 8) {
                int ee[8]; unsigned int uu[8];
#pragma unroll
                for (int q = 0; q < 8; q++) ee[q] = __shfl(vl, t + q, 32);
#pragma unroll
                for (int q = 0; q < 8; q++) uu[q] = emean1b[ee[q] * 32 + lane];
#pragma unroll
                for (int q = 0; q < 8; q++) {
                    accx += bf2f((unsigned short)(uu[q] & 0xFFFFu));
                    accy += bf2f((unsigned short)(uu[q] >> 16));
                }
            }
            for (; t < m; t++) {
                int e = __shfl(vl, t, 32);
                unsigned int u = emean1b[e * 32 + lane];
                accx += bf2f((unsigned short)(u & 0xFFFFu));
                accy += bf2f((unsigned short)(u >> 16));
            }
        }
        unsafeAtomicAdd(o64 + (size_t)n * 64 + 2 * lane,     accx);
        unsafeAtomicAdd(o64 + (size_t)n * 64 + 2 * lane + 1, accy);
    }
}

// ---------------------------------------------------------------------------
// final: out[n][c] = o64[n][c] + bout[c]   (projection already folded)
__global__ __launch_bounds__(256) void final_out(
    const float* __restrict__ o64, const void* __restrict__ bout,
    void* __restrict__ out, const unsigned int* __restrict__ xprobe)
{
    const int isf32 = probe_isf32(xprobe);
    int t = blockIdx.x * 256 + threadIdx.x;   // t < N_NODES*32
    int c = t & 31;
    float2 v = *(const float2*)(o64 + (size_t)t * 2);
    float r0 = v.x + loadS(bout, 2 * c, isf32);
    float r1 = v.y + loadS(bout, 2 * c + 1, isf32);
    if (isf32) ((float2*)out)[t] = make_float2(r0, r1);
    else ((unsigned int*)out)[t] = ((unsigned int)f2bfu(r1) << 16) | f2bfu(r0);
}

// ---------------------------------------------------------------------------
extern "C" void kernel_launch(void* const* d_in, const int* in_sizes, int n_in,
                              void* d_out, int out_size, void* d_ws, size_t ws_size,
                              hipStream_t stream)
{
    const void* x  = d_in[0];
    const int* idx1 = (const int*)d_in[1];
    const int* idx2 = (const int*)d_in[2];
    const void* W1 = d_in[3];
    const void* b1 = d_in[4];
    const void* W2 = d_in[5];
    const void* b2 = d_in[6];
    const void* Wo = d_in[7];
    const void* bo = d_in[8];

    const int nnz1 = in_sizes[1] / 2;
    const int nnz2 = in_sizes[2] / 2;
    const int nblk = (nnz2 + CHUNK - 1) / CHUNK;

    // ---- workspace layout (units of 4 bytes) ----
    float* ws = (float*)d_ws;
    unsigned short* xtP1b = (unsigned short*)ws;              // [0 .. 320,000)
    unsigned int*   xtP1u = (unsigned int*)xtP1b;
    unsigned short* xtP2b = (unsigned short*)(ws + 320000);   // [.. 640,000)
    unsigned int*   xtP2u = (unsigned int*)xtP2b;
    float* o64    = ws + 640000;            // 640,000   --- zero span start
    int*   fill1e = (int*)(ws + 1280000);   //   4,000
    int*   fill1n = (int*)(ws + 1284000);   //  10,000
    float* esum2f = ws + 1294000;           // 256,000   --- zero span end
    // zero span: [640,000 .. 1,550,000) = 910,000 floats = 227,500 f4
    int* cnt2  = (int*)(ws + 1550000);      //  4,000  --- int-zero span (18,000)
    int* cnt1e = (int*)(ws + 1554000);      //  4,000
    int* cnt1n = (int*)(ws + 1558000);      // 10,000
    int* ptr2  = (int*)(ws + 1568000);      //  4,001
    int* ptr1e = (int*)(ws + 1572004);      //  4,001
    int* ptr1n = (int*)(ws + 1576008);      // 10,001
    int* nptr  = (int*)(ws + 1586012);      // 10,001
    float* weff1 = ws + 1596016;            //  8,192
    float* weff2 = ws + 1604208;            //  8,192
    float* beff1 = ws + 1612400;            //     64
    float* beff2 = ws + 1612464;            //     64
    unsigned int* emean2b = (unsigned int*)(ws + 1612528);   // 128,000
    unsigned int* emean1b = (unsigned int*)(ws + 1740528);   // 128,000
    unsigned short* nodelist2 = (unsigned short*)(ws + 1868528);
    const size_t nl2u = ((size_t)nnz2 + 1) / 2;
    unsigned short* nodelist1 = (unsigned short*)(ws + 1868528 + nl2u);
    const size_t nl1u = ((size_t)nnz1 + 1) / 2;
    unsigned short* edgelist1 = (unsigned short*)(ws + 1868528 + nl2u + nl1u);
    const size_t bh_off = (1868528 + nl2u + 2 * nl1u + 7) & ~(size_t)7;
    int* bh = (int*)(ws + bh_off);

    const int segB = ((nnz2 + SEG - 1) / SEG + 3) / 4;   // waves/4 per block

    // 0) W_eff precompute + zero count arrays
    weff_zero<<<3, 256, 0, stream>>>(Wo, W1, b1, W2, b2,
                                     weff1, beff1, weff2, beff2,
                                     cnt2, (const unsigned int*)x);

    // 1) mega-prep: hist2 | hist1 | gemm(64) | zero | nptr
    prep<<<nblk + 8 + G_GEMM + G_ZERO + G_NPTR, 256, 0, stream>>>(
        x, weff1, beff1, weff2, beff2, xtP1b, xtP2b,
        idx1, nnz1, idx2, nnz2,
        nptr, (float4*)(ws + 640000), 227500, bh, cnt2, cnt1e, cnt1n, nblk);

    // 2) scans: ptr2 | ptr1e | ptr1n
    scans3<<<3, 256, 0, stream>>>(cnt2, ptr2, cnt1e, ptr1e, cnt1n, ptr1n);

    // 3) scan_blocks | fill_both
    sb_fb<<<16 + (nnz1 + 255) / 256, 256, 0, stream>>>(
        ptr2, bh, nblk, idx1, nnz1, ptr1e, fill1e, nodelist1,
        ptr1n, fill1n, edgelist1);

    // 4) scale-2 placement (1024-thread blocks)
    place_entries<<<nblk, 1024, 0, stream>>>(idx2, nnz2, bh, nodelist2);

    // 5) edge gathers: s2 quad-entry seg sums | s1 per-edge mean
    edge_gather<<<segB + N_EDGES / 8, 256, 0, stream>>>(
        nodelist2, ptr2, nnz2, xtP2u, esum2f, segB,
        nodelist1, ptr1e, xtP1u, emean1b);

    // 6) s2 mean + pack
    pack2<<<(N_EDGES * 32) / 256, 256, 0, stream>>>(esum2f, ptr2, emean2b);

    // 7) node gathers: s2 quad-entry seg sums | s1 per-node (atomic into o64)
    node_gather<<<segB + N_NODES / 8, 256, 0, stream>>>(
        idx2 + nnz2, nptr, nnz2, emean2b, o64, segB,
        edgelist1, ptr1n, emean1b);

    // 8) final bias-add + convert
    final_out<<<(N_NODES * 32) / 256, 256, 0, stream>>>(o64, bo, d_out,
                                                        (const unsigned int*)x);
}

// Round 14
// 234.757 us; speedup vs baseline: 1.2338x; 1.0224x over previous
//
#include <hip/hip_runtime.h>
#include <hip/hip_bf16.h>

// Problem constants (fixed by the reference's setup_inputs)
#define N_NODES 10000
#define N_EDGES 4000
#define IN_CH   128
#define HOC     128   // HEADS*OUT_CH (internal width of W1/W2)
#define OUT_CH  64    // folded gather width = OUT_CH
#define CHUNK   16384 // entries per counting-sort block (scale-2)
#define SEG     128   // entries per gather wave-segment (scale-2)

#define G_GEMM  625   // N_NODES/16
#define G_ZERO  512
#define G_NPTR  40    // ceil(10001/256)

__device__ __forceinline__ float bf2f(unsigned short u) {
    union { unsigned int i; float f; } v;
    v.i = ((unsigned int)u) << 16;
    return v.f;
}
__device__ __forceinline__ unsigned short f2bfu(float f) {
    union { __hip_bfloat16 h; unsigned short u; } v;
    v.h = __float2bfloat16(f);
    return v.u;
}

// load 8 consecutive float values from either fp32 or packed-bf16 storage.
__device__ __forceinline__ void load8(const void* base, size_t eoff, int isf32,
                                      float o[8]) {
    if (isf32) {
        const float4* q = (const float4*)((const float*)base + eoff);
        float4 a = q[0], b = q[1];
        o[0]=a.x; o[1]=a.y; o[2]=a.z; o[3]=a.w;
        o[4]=b.x; o[5]=b.y; o[6]=b.z; o[7]=b.w;
    } else {
        uint4 v = *(const uint4*)((const unsigned short*)base + eoff);
        const unsigned short* pv = (const unsigned short*)&v;
#pragma unroll
        for (int q = 0; q < 8; q++) o[q] = bf2f(pv[q]);
    }
}

__device__ __forceinline__ float loadS(const void* base, int i, int isf32) {
    return isf32 ? ((const float*)base)[i] : bf2f(((const unsigned short*)base)[i]);
}

// Per-wave inline dtype probe of x's first 512 bytes. 1 = fp32, 0 = bf16.
__device__ __forceinline__ int probe_isf32(const unsigned int* __restrict__ x) {
    const int lane = threadIdx.x & 63;
    unsigned int w0 = x[lane * 2], w1 = x[lane * 2 + 1];
    int h = 0, z = 0;
    {
        unsigned int lo = w0 & 0xFFFFu;
        if (lo == 0u) z++; else if (((lo >> 7) & 0xFF) >= 0x90u) h++;
        lo = w1 & 0xFFFFu;
        if (lo == 0u) z++; else if (((lo >> 7) & 0xFF) >= 0x90u) h++;
    }
    unsigned long long bh = __ballot(h > 0);
    unsigned long long bz = __ballot(z == 2);
    return (__popcll(bh) > 8 || __popcll(bz) > 50) ? 1 : 0;
}

// add 4 bf16 channels (one uint2) into acc[4]
__device__ __forceinline__ void add4(float acc[4], uint2 u) {
    acc[0] += bf2f((unsigned short)(u.x & 0xFFFFu));
    acc[1] += bf2f((unsigned short)(u.x >> 16));
    acc[2] += bf2f((unsigned short)(u.y & 0xFFFFu));
    acc[3] += bf2f((unsigned short)(u.y >> 16));
}

// cross-sub reduce (4 subs share channel quad ch4) + single atomic flush
__device__ __forceinline__ void flushq(float acc[4], float* __restrict__ dst,
                                       int g, int ch4, int sub) {
#pragma unroll
    for (int q = 0; q < 4; q++) {
        acc[q] += __shfl_xor(acc[q], 16);
        acc[q] += __shfl_xor(acc[q], 32);
    }
    if (sub == 0) {
        float* p = dst + (size_t)g * 64 + ch4 * 4;
        unsafeAtomicAdd(p + 0, acc[0]);
        unsafeAtomicAdd(p + 1, acc[1]);
        unsafeAtomicAdd(p + 2, acc[2]);
        unsafeAtomicAdd(p + 3, acc[3]);
    }
#pragma unroll
    for (int q = 0; q < 4; q++) acc[q] = 0.f;
}

// ---------------------------------------------------------------------------
// Dispatch 0: W_eff_s = 0.5*Wout@W_s (64x128), beff_s = 0.5*Wout@b_s, and
// zero the 18000-int count block. Blocks 0/1 = scales; block 2 = zero.
__global__ __launch_bounds__(256) void weff_zero(
    const void* __restrict__ Wout,
    const void* __restrict__ W1, const void* __restrict__ b1,
    const void* __restrict__ W2, const void* __restrict__ b2,
    float* __restrict__ weff1, float* __restrict__ beff1,
    float* __restrict__ weff2, float* __restrict__ beff2,
    int* __restrict__ cntz, const unsigned int* __restrict__ xprobe)
{
    if (blockIdx.x == 2) {
        for (int t = threadIdx.x; t < 18000; t += 256) cntz[t] = 0;
        return;
    }
    const int s = blockIdx.x;
    const void* Ws = s ? W2 : W1;
    const void* bs = s ? b2 : b1;
    float* outW = s ? weff2 : weff1;
    float* outb = s ? beff2 : beff1;
    const int isf32 = probe_isf32(xprobe);

    __shared__ float wsh[64][IN_CH];     // 32 KB: 64 rows of W_s at a time
    const int o  = threadIdx.x >> 2;       // 0..63 output row
    const int i0 = (threadIdx.x & 3) * 32; // column chunk
    float acc[32];
#pragma unroll
    for (int k = 0; k < 32; k++) acc[k] = 0.f;

    for (int pass = 0; pass < 2; pass++) {
        for (int r = 0; r < 4; r++) {
            int idx = r * 2048 + threadIdx.x * 8;
            float v[8];
            load8(Ws, (size_t)pass * 8192 + idx, isf32, v);
            float* d = &wsh[0][0] + idx;
#pragma unroll
            for (int q = 0; q < 8; q++) d[q] = v[q];
        }
        __syncthreads();
        for (int h = 0; h < 64; h++) {
            float wo = loadS(Wout, o * 128 + pass * 64 + h, isf32);
            const float* wr = &wsh[h][i0];
#pragma unroll
            for (int k = 0; k < 32; k++) acc[k] += wo * wr[k];
        }
        __syncthreads();
    }
#pragma unroll
    for (int k = 0; k < 32; k++) outW[o * 128 + i0 + k] = 0.5f * acc[k];

    if (threadIdx.x < 64) {
        float a = 0.f;
        for (int h = 0; h < 128; h++)
            a += loadS(Wout, threadIdx.x * 128 + h, isf32) * loadS(bs, h, isf32);
        outb[threadIdx.x] = 0.5f * a;
    }
}

// ---------------------------------------------------------------------------
// MEGA-PREP: block-range fused, all roles mutually independent.
__global__ __launch_bounds__(256) void prep(
    const void* __restrict__ x,
    const float* __restrict__ weff1, const float* __restrict__ beff1,
    const float* __restrict__ weff2, const float* __restrict__ beff2,
    unsigned short* __restrict__ xtP1b, unsigned short* __restrict__ xtP2b,
    const int* __restrict__ idx1, int nnz1,
    const int* __restrict__ idx2, int nnz2,
    int* __restrict__ nptr, float4* __restrict__ zerobase, int zeroN4,
    int* __restrict__ bh, int* __restrict__ cnt2,
    int* __restrict__ cnt1e, int* __restrict__ cnt1n, int nblk)
{
    __shared__ __align__(16) char smem[40000];
    int b = blockIdx.x;

    if (b < nblk) {                     // ---- hist2 ----
        int* h = (int*)smem;
        for (int t = threadIdx.x; t < N_EDGES; t += 256) h[t] = 0;
        __syncthreads();
        const int lo = b * CHUNK;
        const int hi = min(nnz2, lo + CHUNK);
        for (int i = lo + threadIdx.x; i < hi; i += 256)
            atomicAdd(&h[idx2[nnz2 + i]], 1);
        __syncthreads();
        int* dst = bh + (size_t)b * N_EDGES;
        for (int t = threadIdx.x; t < N_EDGES; t += 256) {
            int v = h[t];
            dst[t] = v;
            if (v) atomicAdd(&cnt2[t], v);
        }
        return;
    }
    b -= nblk;

    if (b < 8) {                        // ---- hist1 ----
        const int isEdge = b < 4;
        const int bid = isEdge ? b : (b - 4);
        const int nb = isEdge ? N_EDGES : N_NODES;
        const int* src = isEdge ? (idx1 + nnz1) : idx1;
        int* dst = isEdge ? cnt1e : cnt1n;
        int* h = (int*)smem;
        for (int t = threadIdx.x; t < nb; t += 256) h[t] = 0;
        __syncthreads();
        for (int i = bid * 256 + threadIdx.x; i < nnz1; i += 4 * 256)
            atomicAdd(&h[src[i]], 1);
        __syncthreads();
        for (int t = threadIdx.x; t < nb; t += 256) {
            int v = h[t];
            if (v) atomicAdd(&dst[t], v);
        }
        return;
    }
    b -= 8;

    if (b < G_GEMM) {                   // ---- gemm (64-col folded) ----
        const int isf32 = probe_isf32((const unsigned int*)x);
        float (*xs)[IN_CH] = (float (*)[IN_CH])smem;
        const int n0 = b * 16;
        {
            float v[8];
            load8(x, (size_t)n0 * IN_CH + (size_t)threadIdx.x * 8, isf32, v);
            float* dst = &xs[0][0] + threadIdx.x * 8;
#pragma unroll
            for (int q = 0; q < 8; q++) dst[q] = v[q];
        }
        __syncthreads();

        const int g   = threadIdx.x >> 7;      // node half
        const int sel = (threadIdx.x >> 6) & 1;
        const int j   = threadIdx.x & 63;      // output column
        const float* WE = sel ? weff2 : weff1;
        const float* BE = sel ? beff2 : beff1;
        unsigned short* xtP = sel ? xtP2b : xtP1b;

        float acc[8];
#pragma unroll
        for (int m = 0; m < 8; m++) acc[m] = 0.f;

        const float4* Wr = (const float4*)(WE + (size_t)j * 128);
        for (int kk = 0; kk < 16; kk++) {
            float4 a = Wr[kk * 2], c = Wr[kk * 2 + 1];
            float w[8] = {a.x, a.y, a.z, a.w, c.x, c.y, c.z, c.w};
#pragma unroll
            for (int m = 0; m < 8; m++) {
                const float* xr = &xs[g * 8 + m][kk * 8];
                acc[m] += xr[0]*w[0] + xr[1]*w[1] + xr[2]*w[2] + xr[3]*w[3]
                        + xr[4]*w[4] + xr[5]*w[5] + xr[6]*w[6] + xr[7]*w[7];
            }
        }
        const float bias = BE[j];
#pragma unroll
        for (int m = 0; m < 8; m++)
            xtP[(size_t)(n0 + g * 8 + m) * 64 + j] = f2bfu(acc[m] + bias);
        return;
    }
    b -= G_GEMM;

    if (b < G_ZERO) {                   // ---- zero ----
        for (int t = b * 256 + threadIdx.x; t < zeroN4; t += G_ZERO * 256)
            zerobase[t] = make_float4(0.f, 0.f, 0.f, 0.f);
        return;
    }
    b -= G_ZERO;

    {                                   // ---- nptr ----
        int n = b * 256 + threadIdx.x;
        if (n > N_NODES) return;
        int lo = 0, hi = nnz2;
        while (lo < hi) { int mid = (lo + hi) >> 1; if (idx2[mid] < n) lo = mid + 1; else hi = mid; }
        nptr[n] = lo;
    }
}

// ---------------------------------------------------------------------------
// 3-block exclusive scans over the count arrays.
__global__ __launch_bounds__(256) void scans3(
    const int* __restrict__ cnt2, int* __restrict__ ptr2,
    const int* __restrict__ cnt1e, int* __restrict__ ptr1e,
    const int* __restrict__ cnt1n, int* __restrict__ ptr1n)
{
    const int* cnt; int* ptr; int nb;
    if (blockIdx.x == 0)      { cnt = cnt2;  ptr = ptr2;  nb = N_EDGES; }
    else if (blockIdx.x == 1) { cnt = cnt1e; ptr = ptr1e; nb = N_EDGES; }
    else                      { cnt = cnt1n; ptr = ptr1n; nb = N_NODES; }
    __shared__ int part[256];
    const int t = threadIdx.x;
    const int K = (nb + 255) >> 8;
    const int base = t * K;
    int s = 0;
    for (int q = 0; q < K; q++) {
        int i = base + q;
        s += (i < nb) ? cnt[i] : 0;
    }
    part[t] = s;
    __syncthreads();
    for (int d = 1; d < 256; d <<= 1) {
        int v = (t >= d) ? part[t - d] : 0;
        __syncthreads();
        part[t] += v;
        __syncthreads();
    }
    int run = part[t] - s;
    for (int q = 0; q < K; q++) {
        int i = base + q;
        if (i < nb) { ptr[i] = run; run += cnt[i]; }
    }
    if (t == 255) ptr[nb] = part[255];
}

// ---------------------------------------------------------------------------
// Fused: scan_blocks (batched-prefetch, breaks serial L2 chain) + fill_both
__global__ __launch_bounds__(256) void sb_fb(
    const int* __restrict__ ptr2, int* __restrict__ bh, int nblk,
    const int* __restrict__ idx1, int nnz1,
    const int* __restrict__ ptr1e, int* __restrict__ fill1e,
    unsigned short* __restrict__ nodelist1,
    const int* __restrict__ ptr1n, int* __restrict__ fill1n,
    unsigned short* __restrict__ edgelist1)
{
    int b = blockIdx.x;
    if (b < 16) {                       // scan_blocks: thread per edge
        int e = b * 256 + threadIdx.x;
        if (e >= N_EDGES) return;
        int run = ptr2[e];
        int k = 0;
        for (; k + 8 <= nblk; k += 8) {
            int v[8];
#pragma unroll
            for (int q = 0; q < 8; q++)
                v[q] = bh[(size_t)(k + q) * N_EDGES + e];   // 8 indep loads
#pragma unroll
            for (int q = 0; q < 8; q++) {
                bh[(size_t)(k + q) * N_EDGES + e] = run;
                run += v[q];
            }
        }
        for (; k < nblk; k++) {
            int i = k * N_EDGES + e;
            int t = bh[i];
            bh[i] = run;
            run += t;
        }
        return;
    }
    b -= 16;
    int i = b * 256 + threadIdx.x;
    if (i >= nnz1) return;
    int n = idx1[i];
    int e = idx1[nnz1 + i];
    int se = atomicAdd(&fill1e[e], 1);
    nodelist1[ptr1e[e] + se] = (unsigned short)n;
    int sn = atomicAdd(&fill1n[n], 1);
    edgelist1[ptr1n[n] + sn] = (unsigned short)e;
}

// ---------------------------------------------------------------------------
// scale-2 placement with LDS slot counters; 1024-thread blocks (16 waves) so
// each thread handles only 16 entries -> latency-hidden.
__global__ __launch_bounds__(1024) void place_entries(
    const int* __restrict__ idx, int nnz, const int* __restrict__ bh,
    unsigned short* __restrict__ nodelist)
{
    __shared__ int lh[N_EDGES];
    for (int t = threadIdx.x; t < N_EDGES; t += 1024) lh[t] = 0;
    __syncthreads();
    const int b = blockIdx.x;
    const int lo = b * CHUNK;
    const int hi = min(nnz, lo + CHUNK);
    const int* bhb = bh + (size_t)b * N_EDGES;
    for (int i = lo + threadIdx.x; i < hi; i += 1024) {
        int n = idx[i];
        int e = idx[nnz + i];
        int s = atomicAdd(&lh[e], 1);
        nodelist[bhb[e] + s] = (unsigned short)n;
    }
}

// ---------------------------------------------------------------------------
// Fused edge gathers, 64 channels.
//  [0, segB): s2 QUAD-entry segment gather (wave = 4 entries/load, uint2/lane)
//  [segB, segB+500): s1 half-wave-per-edge mean (fused div+pack)
__global__ __launch_bounds__(256) void edge_gather(
    const unsigned short* __restrict__ nodelist2, const int* __restrict__ ptr2,
    int nnz2, const unsigned int* __restrict__ xtP2u, float* __restrict__ esum2f,
    int segB,
    const unsigned short* __restrict__ nodelist1, const int* __restrict__ ptr1e,
    const unsigned int* __restrict__ xtP1u, unsigned int* __restrict__ emean1b)
{
    int b = blockIdx.x;
    if (b < segB) {
        const int lane = threadIdx.x & 63;
        const int sub  = lane >> 4;    // entry-in-quad
        const int ch4  = lane & 15;    // uint2 channel quad
        const int wave = (b * 256 + threadIdx.x) >> 6;
        const int s = wave * SEG;
        if (s >= nnz2) return;
        const int e_end = min(nnz2, s + SEG);
        const uint2* src2 = (const uint2*)xtP2u;

        int lo = 0, hi = N_EDGES;
        while (lo < hi) { int mid = (lo + hi) >> 1; if (ptr2[mid] <= s) lo = mid + 1; else hi = mid; }
        int g = lo - 1;
        int next = ptr2[g + 1];

        float acc[4] = {0.f, 0.f, 0.f, 0.f};
        for (int i = s; i < e_end; i += 64) {
            const int m = min(64, e_end - i);
            int vl = (i + lane < e_end) ? (int)nodelist2[i + lane] : 0;
            int j = 0;
            while (j < m) {
                while (i + j >= next) {
                    flushq(acc, esum2f, g, ch4, sub);
                    g++;
                    next = ptr2[g + 1];
                }
                int run = min(m - j, next - (i + j));
                int t = 0;
                for (; t + 15 < run; t += 16) {      // 4 indep quad loads
                    int n0 = __shfl(vl, j + t + sub);
                    int n1 = __shfl(vl, j + t + 4 + sub);
                    int n2 = __shfl(vl, j + t + 8 + sub);
                    int n3 = __shfl(vl, j + t + 12 + sub);
                    uint2 u0 = src2[(size_t)n0 * 16 + ch4];
                    uint2 u1 = src2[(size_t)n1 * 16 + ch4];
                    uint2 u2 = src2[(size_t)n2 * 16 + ch4];
                    uint2 u3 = src2[(size_t)n3 * 16 + ch4];
                    add4(acc, u0); add4(acc, u1); add4(acc, u2); add4(acc, u3);
                }
                for (; t + 3 < run; t += 4) {
                    int n0 = __shfl(vl, j + t + sub);
                    uint2 u0 = src2[(size_t)n0 * 16 + ch4];
                    add4(acc, u0);
                }
                if (t < run) {                        // tail: 1..3 entries
                    int r = run - t;
                    int n0 = __shfl(vl, j + t + (sub < r ? sub : r - 1));
                    uint2 u0 = src2[(size_t)n0 * 16 + ch4];
                    if (sub < r) add4(acc, u0);
                }
                j += run;
            }
        }
        flushq(acc, esum2f, g, ch4, sub);
        return;
    }
    b -= segB;
    {   // scale-1 half-wave-per-edge mean
        const int lane = threadIdx.x & 31;
        const int e = b * 8 + (threadIdx.x >> 5);
        const int lo = ptr1e[e], hi = ptr1e[e + 1];
        float accx = 0.f, accy = 0.f;
        for (int base = lo; base < hi; base += 32) {
            const int m = min(32, hi - base);
            int vl = (base + lane < hi) ? (int)nodelist1[base + lane] : 0;
            int t = 0;
            for (; t + 7 < m; t += 8) {
                int nn[8]; unsigned int uu[8];
#pragma unroll
                for (int q = 0; q < 8; q++) nn[q] = __shfl(vl, t + q, 32);
#pragma unroll
                for (int q = 0; q < 8; q++) uu[q] = xtP1u[nn[q] * 32 + lane];
#pragma unroll
                for (int q = 0; q < 8; q++) {
                    accx += bf2f((unsigned short)(uu[q] & 0xFFFFu));
                    accy += bf2f((unsigned short)(uu[q] >> 16));
                }
            }
            for (; t < m; t++) {
                int n = __shfl(vl, t, 32);
                unsigned int u = xtP1u[n * 32 + lane];
                accx += bf2f((unsigned short)(u & 0xFFFFu));
                accy += bf2f((unsigned short)(u >> 16));
            }
        }
        const float inv = 1.f / fmaxf((float)(hi - lo), 1.f);
        emean1b[e * 32 + lane] =
            ((unsigned int)f2bfu(accy * inv) << 16) | f2bfu(accx * inv);
    }
}

// ---------------------------------------------------------------------------
// s2 mean + pack to bf16x2 (counts from ptr2 diffs); 4000x32 uints
__global__ __launch_bounds__(256) void pack2(
    const float* __restrict__ esum2f, const int* __restrict__ ptr2,
    unsigned int* __restrict__ emean2b)
{
    int t = blockIdx.x * 256 + threadIdx.x;   // t < N_EDGES*32
    int e = t >> 5;
    float inv = 1.f / fmaxf((float)(ptr2[e + 1] - ptr2[e]), 1.f);
    float2 v = *(const float2*)(esum2f + (size_t)t * 2);
    emean2b[t] = ((unsigned int)f2bfu(v.y * inv) << 16) | f2bfu(v.x * inv);
}

// ---------------------------------------------------------------------------
// Fused node gathers into zeroed o64 (both scales atomic):
//  [0, segB): s2 QUAD-entry segment gather; [segB, +1250): s1 half-wave/node.
__global__ __launch_bounds__(256) void node_gather(
    const int* __restrict__ vals2, const int* __restrict__ nptr, int nnz2,
    const unsigned int* __restrict__ emean2b, float* __restrict__ o64, int segB,
    const unsigned short* __restrict__ edgelist1, const int* __restrict__ ptr1n,
    const unsigned int* __restrict__ emean1b)
{
    int b = blockIdx.x;
    if (b < segB) {
        const int lane = threadIdx.x & 63;
        const int sub  = lane >> 4;
        const int ch4  = lane & 15;
        const int wave = (b * 256 + threadIdx.x) >> 6;
        const int s = wave * SEG;
        if (s >= nnz2) return;
        const int e_end = min(nnz2, s + SEG);
        const uint2* src2 = (const uint2*)emean2b;

        int lo = 0, hi = N_NODES;
        while (lo < hi) { int mid = (lo + hi) >> 1; if (nptr[mid] <= s) lo = mid + 1; else hi = mid; }
        int g = lo - 1;
        int next = nptr[g + 1];

        float acc[4] = {0.f, 0.f, 0.f, 0.f};
        for (int i = s; i < e_end; i += 64) {
            const int m = min(64, e_end - i);
            int vl = (i + lane < e_end) ? vals2[i + lane] : 0;
            int j = 0;
            while (j < m) {
                while (i + j >= next) {
                    flushq(acc, o64, g, ch4, sub);
                    g++;
                    next = nptr[g + 1];
                }
                int run = min(m - j, next - (i + j));
                int t = 0;
                for (; t + 15 < run; t += 16) {
                    int e0 = __shfl(vl, j + t + sub);
                    int e1 = __shfl(vl, j + t + 4 + sub);
                    int e2 = __shfl(vl, j + t + 8 + sub);
                    int e3 = __shfl(vl, j + t + 12 + sub);
                    uint2 u0 = src2[(size_t)e0 * 16 + ch4];
                    uint2 u1 = src2[(size_t)e1 * 16 + ch4];
                    uint2 u2 = src2[(size_t)e2 * 16 + ch4];
                    uint2 u3 = src2[(size_t)e3 * 16 + ch4];
                    add4(acc, u0); add4(acc, u1); add4(acc, u2); add4(acc, u3);
                }
                for (; t + 3 < run; t += 4) {
                    int e0 = __shfl(vl, j + t + sub);
                    uint2 u0 = src2[(size_t)e0 * 16 + ch4];
                    add4(acc, u0);
                }
                if (t < run) {
                    int r = run - t;
                    int e0 = __shfl(vl, j + t + (sub < r ? sub : r - 1));
                    uint2 u0 = src2[(size_t)e0 * 16 + ch4];
                    if (sub < r) add4(acc, u0);
                }
                j += run;
            }
        }
        flushq(acc, o64, g, ch4, sub);
        return;
    }
    b -= segB;
    {   // scale-1 half-wave-per-node
        const int lane = threadIdx.x & 31;
        const int n = b * 8 + (threadIdx.x >> 5);
        const int lo = ptr1n[n], hi = ptr1n[n + 1];
        if (lo == hi) return;
        float accx = 0.f, accy = 0.f;
        for (int base = lo; base < hi; base += 32) {
            const int m = min(32, hi - base);
            int vl = (base + lane < hi) ? (int)edgelist1[base + lane] : 0;
            int t = 0;
            for (; t + 7 < m; t += 8) {
                int ee[8]; unsigned int uu[8];
#pragma unroll
                for (int q = 0; q < 8; q++) ee[q] = __shfl(vl, t + q, 32);
#pragma unroll
                for (int q = 0; q < 8; q++) uu[q] = emean1b[ee[q] * 32 + lane];
#pragma unroll
                for (int q = 0; q < 8; q++) {
                    accx += bf2f((unsigned short)(uu[q] & 0xFFFFu));
                    accy += bf2f((unsigned short)(uu[q] >> 16));
                }
            }
            for (; t < m; t++) {
                int e = __shfl(vl, t, 32);
                unsigned int u = emean1b[e * 32 + lane];
                accx += bf2f((unsigned short)(u & 0xFFFFu));
                accy += bf2f((unsigned short)(u >> 16));
            }
        }
        unsafeAtomicAdd(o64 + (size_t)n * 64 + 2 * lane,     accx);
        unsafeAtomicAdd(o64 + (size_t)n * 64 + 2 * lane + 1, accy);
    }
}

// ---------------------------------------------------------------------------
// final: out[n][c] = o64[n][c] + bout[c]   (projection already folded)
__global__ __launch_bounds__(256) void final_out(
    const float* __restrict__ o64, const void* __restrict__ bout,
    void* __restrict__ out, const unsigned int* __restrict__ xprobe)
{
    const int isf32 = probe_isf32(xprobe);
    int t = blockIdx.x * 256 + threadIdx.x;   // t < N_NODES*32
    int c = t & 31;
    float2 v = *(const float2*)(o64 + (size_t)t * 2);
    float r0 = v.x + loadS(bout, 2 * c, isf32);
    float r1 = v.y + loadS(bout, 2 * c + 1, isf32);
    if (isf32) ((float2*)out)[t] = make_float2(r0, r1);
    else ((unsigned int*)out)[t] = ((unsigned int)f2bfu(r1) << 16) | f2bfu(r0);
}

// ---------------------------------------------------------------------------
extern "C" void kernel_launch(void* const* d_in, const int* in_sizes, int n_in,
                              void* d_out, int out_size, void* d_ws, size_t ws_size,
                              hipStream_t stream)
{
    const void* x  = d_in[0];
    const int* idx1 = (const int*)d_in[1];
    const int* idx2 = (const int*)d_in[2];
    const void* W1 = d_in[3];
    const void* b1 = d_in[4];
    const void* W2 = d_in[5];
    const void* b2 = d_in[6];
    const void* Wo = d_in[7];
    const void* bo = d_in[8];

    const int nnz1 = in_sizes[1] / 2;
    const int nnz2 = in_sizes[2] / 2;
    const int nblk = (nnz2 + CHUNK - 1) / CHUNK;

    // ---- workspace layout (units of 4 bytes) ----
    float* ws = (float*)d_ws;
    unsigned short* xtP1b = (unsigned short*)ws;              // [0 .. 320,000)
    unsigned int*   xtP1u = (unsigned int*)xtP1b;
    unsigned short* xtP2b = (unsigned short*)(ws + 320000);   // [.. 640,000)
    unsigned int*   xtP2u = (unsigned int*)xtP2b;
    float* o64    = ws + 640000;            // 640,000   --- zero span start
    int*   fill1e = (int*)(ws + 1280000);   //   4,000
    int*   fill1n = (int*)(ws + 1284000);   //  10,000
    float* esum2f = ws + 1294000;           // 256,000   --- zero span end
    // zero span: [640,000 .. 1,550,000) = 910,000 floats = 227,500 f4
    int* cnt2  = (int*)(ws + 1550000);      //  4,000  --- int-zero span (18,000)
    int* cnt1e = (int*)(ws + 1554000);      //  4,000
    int* cnt1n = (int*)(ws + 1558000);      // 10,000
    int* ptr2  = (int*)(ws + 1568000);      //  4,001
    int* ptr1e = (int*)(ws + 1572004);      //  4,001
    int* ptr1n = (int*)(ws + 1576008);      // 10,001
    int* nptr  = (int*)(ws + 1586012);      // 10,001
    float* weff1 = ws + 1596016;            //  8,192
    float* weff2 = ws + 1604208;            //  8,192
    float* beff1 = ws + 1612400;            //     64
    float* beff2 = ws + 1612464;            //     64
    unsigned int* emean2b = (unsigned int*)(ws + 1612528);   // 128,000
    unsigned int* emean1b = (unsigned int*)(ws + 1740528);   // 128,000
    unsigned short* nodelist2 = (unsigned short*)(ws + 1868528);
    const size_t nl2u = ((size_t)nnz2 + 1) / 2;
    unsigned short* nodelist1 = (unsigned short*)(ws + 1868528 + nl2u);
    const size_t nl1u = ((size_t)nnz1 + 1) / 2;
    unsigned short* edgelist1 = (unsigned short*)(ws + 1868528 + nl2u + nl1u);
    const size_t bh_off = (1868528 + nl2u + 2 * nl1u + 7) & ~(size_t)7;
    int* bh = (int*)(ws + bh_off);

    const int segB = ((nnz2 + SEG - 1) / SEG + 3) / 4;   // waves/4 per block

    // 0) W_eff precompute + zero count arrays
    weff_zero<<<3, 256, 0, stream>>>(Wo, W1, b1, W2, b2,
                                     weff1, beff1, weff2, beff2,
                                     cnt2, (const unsigned int*)x);

    // 1) mega-prep: hist2 | hist1 | gemm(64) | zero | nptr
    prep<<<nblk + 8 + G_GEMM + G_ZERO + G_NPTR, 256, 0, stream>>>(
        x, weff1, beff1, weff2, beff2, xtP1b, xtP2b,
        idx1, nnz1, idx2, nnz2,
        nptr, (float4*)(ws + 640000), 227500, bh, cnt2, cnt1e, cnt1n, nblk);

    // 2) scans: ptr2 | ptr1e | ptr1n
    scans3<<<3, 256, 0, stream>>>(cnt2, ptr2, cnt1e, ptr1e, cnt1n, ptr1n);

    // 3) scan_blocks | fill_both
    sb_fb<<<16 + (nnz1 + 255) / 256, 256, 0, stream>>>(
        ptr2, bh, nblk, idx1, nnz1, ptr1e, fill1e, nodelist1,
        ptr1n, fill1n, edgelist1);

    // 4) scale-2 placement (1024-thread blocks)
    place_entries<<<nblk, 1024, 0, stream>>>(idx2, nnz2, bh, nodelist2);

    // 5) edge gathers: s2 quad-entry seg sums | s1 per-edge mean
    edge_gather<<<segB + N_EDGES / 8, 256, 0, stream>>>(
        nodelist2, ptr2, nnz2, xtP2u, esum2f, segB,
        nodelist1, ptr1e, xtP1u, emean1b);

    // 6) s2 mean + pack
    pack2<<<(N_EDGES * 32) / 256, 256, 0, stream>>>(esum2f, ptr2, emean2b);

    // 7) node gathers: s2 quad-entry seg sums | s1 per-node (atomic into o64)
    node_gather<<<segB + N_NODES / 8, 256, 0, stream>>>(
        idx2 + nnz2, nptr, nnz2, emean2b, o64, segB,
        edgelist1, ptr1n, emean1b);

    // 8) final bias-add + convert
    final_out<<<(N_NODES * 32) / 256, 256, 0, stream>>>(o64, bo, d_out,
                                                        (const unsigned int*)x);
}